// Round 4
// baseline (604.784 us; speedup 1.0000x reference)
//
#include <hip/hip_runtime.h>
#include <stdint.h>

// Problem constants (fixed by reference)
#define BATCH 2
#define TLEN  2048
#define DEMB  2048
#define NHQ   16
#define NHKV  4
#define GRP   4
#define DKV   128
#define ATTN_OUT_ELEMS (BATCH*TLEN*DEMB) // 8388608
// d_out layout: [attn_output (8388608 f32) | kv_cache (B,T,4,256) f32 (4194304)]

typedef __bf16 bf16_t;
typedef __attribute__((ext_vector_type(4))) __bf16 bf16x4;
typedef __attribute__((ext_vector_type(8))) __bf16 bf16x8;
typedef __attribute__((ext_vector_type(4))) float f32x4;

__device__ __forceinline__ f32x4 mfma16(bf16x8 a, bf16x8 b, f32x4 c) {
  return __builtin_amdgcn_mfma_f32_16x16x32_bf16(a, b, c, 0, 0, 0);
}

typedef __attribute__((address_space(1))) const unsigned int as1_uint;
typedef __attribute__((address_space(3))) unsigned int as3_uint;
__device__ __forceinline__ void gload_lds16(const void* g, void* l) {
  // 16B per lane, LDS dest = l + lane*16 (wave-uniform base)
  __builtin_amdgcn_global_load_lds((as1_uint*)g, (as3_uint*)l, 16, 0, 0);
}

// ---------------------------------------------------------------------------
// threefry2x32-20, key=(0,1) (jax.random.key(1)), partitionable mode:
// per-element u64 counter (hi=0, lo=ctr), output = x0 ^ x1. Verified R1-R5.
// keep = uniform<0.9  <=>  bits < 0xE6666600 (bit-exact, verified R4/R5).
// ---------------------------------------------------------------------------
__device__ __forceinline__ uint32_t rotl(uint32_t x, int r) {
  return __builtin_amdgcn_alignbit(x, x, 32 - r);
}
__device__ __forceinline__ void tf_round(uint32_t& x0, uint32_t& x1, int r) {
  x0 += x1;
  x1 = rotl(x1, r);
  x1 ^= x0;
}
__device__ __forceinline__ uint32_t threefry_bits(uint32_t ctr) {
  const uint32_t ks1 = 1u, ks2 = 0x1BD11BDBu;
  uint32_t x0 = 0u, x1 = ctr + ks1;
  tf_round(x0,x1,13); tf_round(x0,x1,15); tf_round(x0,x1,26); tf_round(x0,x1,6);
  x0 += ks1; x1 += ks2 + 1u;
  tf_round(x0,x1,17); tf_round(x0,x1,29); tf_round(x0,x1,16); tf_round(x0,x1,24);
  x0 += ks2; x1 += 0u + 2u;
  tf_round(x0,x1,13); tf_round(x0,x1,15); tf_round(x0,x1,26); tf_round(x0,x1,6);
  x0 += 0u;  x1 += ks1 + 3u;
  tf_round(x0,x1,17); tf_round(x0,x1,29); tf_round(x0,x1,16); tf_round(x0,x1,24);
  x0 += ks1; x1 += ks2 + 4u;
  tf_round(x0,x1,13); tf_round(x0,x1,15); tf_round(x0,x1,26); tf_round(x0,x1,6);
  x0 += ks2; x1 += 0u + 5u;
  return x0 ^ x1;
}

// 16 keep-bits for rows [row0,row0+4), cols col0 + {0,16,32,48}; bit (ct*4+r).
__device__ __forceinline__ uint32_t mask16_for(int bqh, int row0, int col0) {
  uint32_t km = 0;
#pragma unroll
  for (int r = 0; r < 4; ++r) {
    uint32_t cb = ((uint32_t)bqh << 22) + ((uint32_t)(row0 + r) << 11)
                + (uint32_t)col0;
#pragma unroll
    for (int ct = 0; ct < 4; ++ct) {
      uint32_t bits = threefry_bits(cb + (uint32_t)(ct * 16));
      km |= (bits < 0xE6666600u ? 1u : 0u) << (ct * 4 + r);
    }
  }
  return km;
}

// ---------------------------------------------------------------------------
// Mask-appendix worker: block j of NB covers units u = u0+j, u0+j+NB, ... < u1.
// Unit u = bqh*528 + p; p -> (qt,kt) triangular. Thread (w,lane) computes the
// same 16 threefry bits attn_flash consumes, store layout
// maskbuf[(u*4 + w)*64 + lane] (uint16). Units are spread across ALL
// pre-attention dispatches sized to their idle VALU capacity (m114: VALU
// waves co-schedule with MFMA/mem waves at ~max, not sum; R3 showed a single
// overloaded host just becomes VALU-bound and extends 1:1).
// ---------------------------------------------------------------------------
__device__ __forceinline__ void mask_units(int j, int NB, int u0, int u1,
                                           uint16_t* __restrict__ maskbuf) {
  const int tid = threadIdx.x;
  const int w = tid >> 6, lane = tid & 63;
  const int lm = lane & 15, lg = lane >> 4;
  for (int u = u0 + j; u < u1; u += NB) {
    int bqh = u / 528, p = u % 528;
    int qt = (int)((sqrtf(8.f * (float)p + 1.f) - 1.f) * 0.5f);
    if ((qt + 1) * (qt + 2) / 2 <= p) ++qt;    // float-rounding fixups
    if (qt * (qt + 1) / 2 > p) --qt;
    int kt = p - qt * (qt + 1) / 2;
    uint32_t km = mask16_for(bqh, qt * 64 + w * 16 + lg * 4, kt * 64 + lm);
    maskbuf[((size_t)u * 4 + w) * 64 + lane] = (uint16_t)km;
  }
}

// Standalone fallback (used only if workspace too small for separate maskbuf).
__global__ __launch_bounds__(256) void gen_mask(uint16_t* __restrict__ maskbuf) {
  mask_units((int)blockIdx.x, (int)gridDim.x, 0, 16896, maskbuf);
}

// ---------------------------------------------------------------------------
// RoPE cos/sin tables [ti=2048][d=64] (double-precision generation).
// ---------------------------------------------------------------------------
__global__ __launch_bounds__(256) void rope_tab(float* __restrict__ ct,
                                                float* __restrict__ st) {
  int i = blockIdx.x * 256 + threadIdx.x;     // 131072 total
  int ti = i >> 6, d = i & 63;
  double theta = exp((double)(-2 * d) * (9.210340371976184 / 128.0)); // ln(1e4)/128
  float tick = (float)ti * (float)theta;
  ct[i] = (float)cos((double)tick);
  st[i] = (float)sin((double)tick);
}

// ---------------------------------------------------------------------------
// fp32 -> bf16 convert (X). No LDS -> mask appendix blocks (units [0,1664))
// co-reside freely with the memory-bound real blocks.
// ---------------------------------------------------------------------------
__global__ __launch_bounds__(256) void cvt_bf16(const float* __restrict__ src,
                                                bf16_t* __restrict__ dst, int n4,
                                                uint16_t* __restrict__ maskbuf) {
  const int bid = blockIdx.x;
  if (bid >= 8192) {                           // mask appendix (fused mode only)
    mask_units(bid - 8192, (int)gridDim.x - 8192, 0, 1664, maskbuf);
    return;
  }
  int i = bid * 256 + threadIdx.x;
  if (i < n4) {
    float4 v = *(const float4*)(src + (size_t)i * 4);
    bf16x4 o = {(bf16_t)v.x, (bf16_t)v.y, (bf16_t)v.z, (bf16_t)v.w};
    *(bf16x4*)(dst + (size_t)i * 4) = o;
  }
}

// ---------------------------------------------------------------------------
// Weight transpose+convert: src f32 [K][N] -> dst bf16 [N][Kd]; one dispatch
// covers wq/wk/wv/wo. Blocks beyond 2560 are mask-appendix blocks (units
// [1664,4416)) soaking idle VALU of this memory-bound dispatch.
// ---------------------------------------------------------------------------
__device__ __forceinline__ void wtrans_body(const float* __restrict__ src,
                                            bf16_t* __restrict__ dst,
                                            int N, int Kd, int k0, int n0) {
  __shared__ float t[64][65];
  const int tid = threadIdx.x;
  const int r = tid >> 4, c4 = tid & 15;
#pragma unroll
  for (int i = 0; i < 4; ++i) {
    float4 v = *(const float4*)(src + (size_t)(k0 + r + i * 16) * N + n0 + c4 * 4);
    t[r + i * 16][c4 * 4 + 0] = v.x; t[r + i * 16][c4 * 4 + 1] = v.y;
    t[r + i * 16][c4 * 4 + 2] = v.z; t[r + i * 16][c4 * 4 + 3] = v.w;
  }
  __syncthreads();
#pragma unroll
  for (int i = 0; i < 4; ++i) {
    int idx = tid + i * 256;
    int rn = idx >> 4, ck = idx & 15;
    bf16x4 o = {(bf16_t)t[ck * 4 + 0][rn], (bf16_t)t[ck * 4 + 1][rn],
                (bf16_t)t[ck * 4 + 2][rn], (bf16_t)t[ck * 4 + 3][rn]};
    *(bf16x4*)(dst + (size_t)(n0 + rn) * Kd + k0 + ck * 4) = o;
  }
}

__global__ __launch_bounds__(256) void wtrans_all(const float* __restrict__ wq,
                                                  const float* __restrict__ wk,
                                                  const float* __restrict__ wv,
                                                  const float* __restrict__ wo,
                                                  bf16_t* __restrict__ dqkv,
                                                  bf16_t* __restrict__ dwo,
                                                  uint16_t* __restrict__ maskbuf) {
  const int bid = blockIdx.x;
  if (bid >= 2560) {                           // mask appendix (fused mode only)
    mask_units(bid - 2560, (int)gridDim.x - 2560, 1664, 4416, maskbuf);
    return;
  }
  const int by = bid >> 5, k0 = (bid & 31) * 64;
  if (by < 32)      wtrans_body(wq, dqkv,                        2048, 2048, k0, by * 64);
  else if (by < 40) wtrans_body(wk, dqkv + (size_t)2048 * 2048,  512,  2048, k0, (by - 32) * 64);
  else if (by < 48) wtrans_body(wv, dqkv + (size_t)2560 * 2048,  512,  2048, k0, (by - 40) * 64);
  else              wtrans_body(wo, dwo,                         2048, 2048, k0, (by - 48) * 64);
}

// ---------------------------------------------------------------------------
// bf16 MFMA GEMM: C[M,N] = Ab[M,K] (row-major) @ Wt[N,K]^T
// 128x128 tile, BK=64, 4 waves, 64x64/wave; col-tile pairing keeps RoPE
// partners (d, d+64) in-wave for MODE 1. global_load_lds(16B) staging with
// XOR chunk swizzle. MODE 0: f32 C. MODE 1: QKV epilogue (RoPE via tables).
// 1-D grid; MODE 1 blocks beyond the GEMM count are mask-appendix blocks
// (units [4416,16896)) co-resident with the latency-bound GEMM blocks
// (3 GEMM blocks/CU use 96KB LDS; 2 appendix blocks fit the remaining 64KB).
// ---------------------------------------------------------------------------
template<int MODE>
__global__ __launch_bounds__(256) void gemm_bf16(
    const bf16_t* __restrict__ Ab, const bf16_t* __restrict__ Wt,
    float* __restrict__ Cout, bf16_t* __restrict__ qbuf,
    bf16_t* __restrict__ Kbuf, float* __restrict__ kvout,
    const float* __restrict__ costab, const float* __restrict__ sintab,
    uint16_t* __restrict__ maskbuf, int M, int N, int K) {
  const int bid = blockIdx.x;
  const int nGemm = (M >> 7) * (N >> 7);
  if (MODE == 1 && bid >= nGemm) {             // mask appendix (fused mode only)
    mask_units(bid - nGemm, (int)gridDim.x - nGemm, 5184, 16896, maskbuf);
    return;
  }
  __shared__ bf16_t As[128 * 64];
  __shared__ bf16_t Bs[128 * 64];
  const int tid = threadIdx.x;
  const int w = tid >> 6, lane = tid & 63;
  const int lm = lane & 15, lg = lane >> 4;
  const int wy = w & 1, wx = w >> 1;
  const int mblk = (bid & 31) * 128, nblk = (bid >> 5) * 128;

  const int srow = lane >> 3;                 // row within 8-row group
  const int schunk = (lane & 7) ^ srow;       // fetch swizzled chunk
  const bf16_t* Ag = Ab + (size_t)(mblk + w * 32 + srow) * K + schunk * 8;
  const bf16_t* Bg = Wt + (size_t)(nblk + w * 32 + srow) * K + schunk * 8;
  bf16_t* AsW = As + (w * 32) * 64;
  bf16_t* BsW = Bs + (w * 32) * 64;

  f32x4 acc[4][4];
#pragma unroll
  for (int i = 0; i < 4; ++i)
#pragma unroll
    for (int j = 0; j < 4; ++j) acc[i][j] = (f32x4)0.0f;

  const int tcol0 = wx * 2;

  for (int k0 = 0; k0 < K; k0 += 64) {
    __syncthreads();
#pragma unroll
    for (int inst = 0; inst < 4; ++inst) {
      gload_lds16(Ag + (size_t)(inst * 8) * K + k0, AsW + inst * 8 * 64);
      gload_lds16(Bg + (size_t)(inst * 8) * K + k0, BsW + inst * 8 * 64);
    }
    asm volatile("s_waitcnt vmcnt(0)" ::: "memory");
    __syncthreads();
#pragma unroll
    for (int ks = 0; ks < 2; ++ks) {
      const int chunk = ((ks * 4 + lg) ^ (lane & 7)) * 8;
      bf16x8 af[4], bfr[4];
#pragma unroll
      for (int i = 0; i < 4; ++i) {
        int mrow = wy * 64 + i * 16 + lm;
        af[i] = *(const bf16x8*)&As[mrow * 64 + chunk];
      }
#pragma unroll
      for (int j = 0; j < 4; ++j) {
        int tc = tcol0 + (j & 1) + (j >> 1) * 4;
        int nrow = tc * 16 + lm;
        bfr[j] = *(const bf16x8*)&Bs[nrow * 64 + chunk];
      }
#pragma unroll
      for (int i = 0; i < 4; ++i)
#pragma unroll
        for (int j = 0; j < 4; ++j) acc[i][j] = mfma16(af[i], bfr[j], acc[i][j]);
    }
  }

  if (MODE == 0) {
#pragma unroll
    for (int i = 0; i < 4; ++i)
#pragma unroll
      for (int j = 0; j < 4; ++j) {
        int tc = tcol0 + (j & 1) + (j >> 1) * 4;
        int col = nblk + tc * 16 + lm;
#pragma unroll
        for (int r = 0; r < 4; ++r) {
          int row = mblk + wy * 64 + i * 16 + lg * 4 + r;
          Cout[(size_t)row * N + col] = acc[i][j][r];
        }
      }
  } else {
    // QKV epilogue with fused RoPE via tables. d in [0,64), partner d+64.
    const float qscale = 0.08838834764831843f;   // 1/sqrt(128)
#pragma unroll
    for (int i = 0; i < 4; ++i) {
#pragma unroll
      for (int r = 0; r < 4; ++r) {
        int row = mblk + wy * 64 + i * 16 + lg * 4 + r;   // bt
        int ti = row & (TLEN - 1), b = row >> 11;
#pragma unroll
        for (int jp = 0; jp < 2; ++jp) {
          float lo = acc[i][jp][r], hi = acc[i][jp + 2][r];
          int d = wx * 32 + jp * 16 + lm;                 // [0,64)
          int nl = nblk + d;                              // low-half global col
          if (nblk < 2048) {                              // q
            int qh = nl >> 7;
            float cs = costab[ti * 64 + d], sn = sintab[ti * 64 + d];
            float o0 = (lo * cs - hi * sn) * qscale;
            float o1 = (hi * cs + lo * sn) * qscale;
            size_t qo = (((size_t)(b * 16 + qh)) * TLEN + ti) * 128 + d;
            qbuf[qo] = (bf16_t)o0; qbuf[qo + 64] = (bf16_t)o1;
          } else if (nblk < 2560) {                       // k
            int hh = (nl - 2048) >> 7;
            float cs = costab[ti * 64 + d], sn = sintab[ti * 64 + d];
            float o0 = lo * cs - hi * sn;
            float o1 = hi * cs + lo * sn;
            size_t ko = (((size_t)(b * 4 + hh)) * TLEN + ti) * 128 + d;
            Kbuf[ko] = (bf16_t)o0; Kbuf[ko + 64] = (bf16_t)o1;
            size_t kvo = (size_t)row * 1024 + hh * 256 + d;
            kvout[kvo] = o0; kvout[kvo + 64] = o1;
          } else {                                        // v
            int hh = (nl - 2560) >> 7;
            size_t kvo = (size_t)row * 1024 + hh * 256 + 128 + d;
            kvout[kvo] = lo; kvout[kvo + 64] = hi;
          }
        }
      }
    }
  }
}

// ---------------------------------------------------------------------------
// V transpose: kv f32 [b][ti][h][128v @ +128] -> Vtb bf16 [b][h][d=128][tj=2048]
// Blocks beyond 256 are mask-appendix blocks (units [4416,5184)).
// ---------------------------------------------------------------------------
__global__ __launch_bounds__(256) void vtrans(const float* __restrict__ kvout,
                                              bf16_t* __restrict__ Vtb,
                                              uint16_t* __restrict__ maskbuf) {
  const int bx = blockIdx.x;          // (b*4+h)*32 + tt
  if (bx >= 256) {                    // mask appendix (fused mode only)
    mask_units(bx - 256, (int)gridDim.x - 256, 4416, 5184, maskbuf);
    return;
  }
  __shared__ bf16_t t[128][72];
  const int tt = bx & 31, bh = bx >> 5;
  const int b = bh >> 2, h = bh & 3;
  const int ti0 = tt * 64;
  const float* src = kvout + ((size_t)b * TLEN + ti0) * 1024 + h * 256 + 128;
  for (int idx = threadIdx.x; idx < 64 * 32; idx += 256) {
    int ti = idx >> 5, c4 = idx & 31;
    float4 v = *(const float4*)(src + (size_t)ti * 1024 + c4 * 4);
    t[c4 * 4 + 0][ti] = (bf16_t)v.x; t[c4 * 4 + 1][ti] = (bf16_t)v.y;
    t[c4 * 4 + 2][ti] = (bf16_t)v.z; t[c4 * 4 + 3][ti] = (bf16_t)v.w;
  }
  __syncthreads();
  bf16_t* dst = Vtb + (size_t)bh * 128 * TLEN + ti0;
  for (int idx = threadIdx.x; idx < 128 * 16; idx += 256) {
    int d = idx >> 4, ck = idx & 15;
    bf16x4 o = {t[d][ck * 4 + 0], t[d][ck * 4 + 1], t[d][ck * 4 + 2], t[d][ck * 4 + 3]};
    *(bf16x4*)(dst + (size_t)d * TLEN + ck * 4) = o;
  }
}

// ---------------------------------------------------------------------------
// Flash attention, bf16 MFMA, LDS-staged K/V shared by all 4 waves.
// Block = (b, qh, 64-row q-tile); wave w owns rows [qt*64+w*16, +16).
// Per 64-col K-tile: cooperative global_load_lds of K (64x128) and V^T
// (128x64) with XOR chunk swizzle; dropout keepmask is a precomputed 2B load
// per lane per tile (mask appendices upstream), fetched while the DMA is in
// flight; two barriers per tile (GEMM pattern). P C->A relayout via
// wave-private LDS strip. Online softmax via 16-lane shfl_xor; exact
// alpha-skip when no row max grows. qt <-> 31-qt pairing balances load.
// ---------------------------------------------------------------------------
#define PSTR 68
__global__ __launch_bounds__(256, 3) void attn_flash(
    const bf16_t* __restrict__ qb, const bf16_t* __restrict__ Kb,
    const bf16_t* __restrict__ Vtb, const uint16_t* __restrict__ maskbuf,
    bf16_t* __restrict__ midb) {
  __shared__ bf16_t Ks[64 * 128];    // [tj][d], 16B chunks XOR-swizzled by tj&15
  __shared__ bf16_t Vs[128 * 64];    // [d][tj], 16B chunks XOR-swizzled by d&7
  __shared__ bf16_t P_lds[64 * PSTR];
  const int tid = threadIdx.x;
  const int w = tid >> 6, lane = tid & 63;
  const int lm = lane & 15, lg = lane >> 4;

  const int bx = blockIdx.x;
  const int bhalf = bx >> 9, idx = bx & 511;
  const int bqh = idx & 31, t4 = idx >> 5;          // t4 in 0..15
  const int qt = bhalf ? (31 - t4) : t4;            // 0..31
  const int qh = bqh & 15, b = bqh >> 4;
  const int h = qh & 3;

  const bf16_t* qbase = qb + (((size_t)(b * 16 + qh)) * TLEN + qt * 64 + w * 16) * 128;
  const bf16_t* kbase = Kb + ((size_t)(b * 4 + h)) * TLEN * 128;
  const bf16_t* vbase = Vtb + ((size_t)(b * 4 + h)) * 128 * TLEN;

  // precomputed dropout mask: one uint16 per (tile, lane); stride 256 per pair
  const int triq = qt * (qt + 1) / 2;
  const uint16_t* mbase = maskbuf + (size_t)bqh * 528 * 256 + w * 64 + lane
                        + (size_t)triq * 256;

  // staging geometry (wave w stages K rows w*16..+15, V rows w*32..+31)
  const int krow_l = lane >> 4;              // 0..3 (4 rows per instr)
  const int kchunk = lane & 15;              // 16 chunks of 16B per 256B row
  const int vrow_l = lane >> 3;              // 0..7 (8 rows per instr)
  const int vchunk = (lane & 7) ^ (vrow_l & 7);
  const bf16_t* ksrc[4]; const bf16_t* vsrc[4];
  bf16_t* kdst[4]; bf16_t* vdst[4];
#pragma unroll
  for (int j = 0; j < 4; ++j) {
    int klr = w * 16 + j * 4 + krow_l;       // tile-local K row
    ksrc[j] = kbase + (size_t)klr * 128 + (size_t)((kchunk ^ (j * 4 + krow_l)) * 8);
    kdst[j] = Ks + (w * 16 + j * 4) * 128;
    int vd = w * 32 + j * 8 + vrow_l;        // V row (d)
    vsrc[j] = vbase + (size_t)vd * TLEN + (size_t)(vchunk * 8);
    vdst[j] = Vs + (w * 32 + j * 8) * 64;
  }

  // Q A-frags (16 rows); q already scaled by 1/sqrt(128)
  bf16x8 qf[4];
#pragma unroll
  for (int kk = 0; kk < 4; ++kk)
    qf[kk] = *(const bf16x8*)(qbase + (size_t)lm * 128 + kk * 32 + lg * 8);

  float mrow[4], lrow[4];
  f32x4 Oacc[8];
#pragma unroll
  for (int r = 0; r < 4; ++r) { mrow[r] = -3.0e38f; lrow[r] = 0.f; }
#pragma unroll
  for (int c = 0; c < 8; ++c) Oacc[c] = (f32x4)0.0f;

  const int row0 = qt * 64 + w * 16;           // wave's first q row
  const int nkt = qt + 1;                      // K-tiles (uniform across waves)
  const float L2E = 1.4426950408889634f;
  bf16_t* Pw = P_lds + (w * 16) * PSTR;

  for (int kt = 0; kt < nkt; ++kt) {
    const int tj0 = kt * 64;
    __syncthreads();                           // prev iter's LDS reads done
    // ---- async stage K,V tiles (8 DMA instrs per wave) ----
#pragma unroll
    for (int j = 0; j < 4; ++j) gload_lds16(ksrc[j] + (size_t)tj0 * 128, kdst[j]);
#pragma unroll
    for (int j = 0; j < 4; ++j) gload_lds16(vsrc[j] + tj0, vdst[j]);

    // ---- precomputed keepmask (2B load, overlaps DMA latency) ----
    uint32_t km = mbase[(size_t)kt * 256];

    asm volatile("s_waitcnt vmcnt(0)" ::: "memory");
    __syncthreads();                           // K/V tile visible to all waves

    // ---- S = Q K^T (K frags from LDS) ----
    f32x4 S[4];
#pragma unroll
    for (int ct = 0; ct < 4; ++ct) {
      S[ct] = (f32x4)0.0f;
      bf16x8 kf[4];
#pragma unroll
      for (int kk = 0; kk < 4; ++kk)
        kf[kk] = *(const bf16x8*)&Ks[(ct * 16 + lm) * 128 + ((kk * 4 + lg) ^ lm) * 8];
#pragma unroll
      for (int kk = 0; kk < 4; ++kk) S[ct] = mfma16(qf[kk], kf[kk], S[ct]);
    }

    // ---- causal mask (diagonal tile only) ----
    if (tj0 + 63 > row0) {
#pragma unroll
      for (int ct = 0; ct < 4; ++ct) {
        int tj = tj0 + ct * 16 + lm;
#pragma unroll
        for (int r = 0; r < 4; ++r) {
          int ti = row0 + lg * 4 + r;
          if (tj > ti) S[ct][r] = -1.0e30f;
        }
      }
    }

    // ---- online softmax (exact alpha-skip when no row max grows) ----
    float alpha[4];
    bool skip;
    {
      float pm[4];
#pragma unroll
      for (int r = 0; r < 4; ++r)
        pm[r] = fmaxf(fmaxf(S[0][r], S[1][r]), fmaxf(S[2][r], S[3][r]));
#pragma unroll
      for (int off = 1; off < 16; off <<= 1)
#pragma unroll
        for (int r = 0; r < 4; ++r) pm[r] = fmaxf(pm[r], __shfl_xor(pm[r], off));
      bool nu = (pm[0] <= mrow[0]) & (pm[1] <= mrow[1]) &
                (pm[2] <= mrow[2]) & (pm[3] <= mrow[3]);
      skip = __all(nu);
      if (!skip) {
#pragma unroll
        for (int r = 0; r < 4; ++r) {
          float mn = fmaxf(mrow[r], pm[r]);
          alpha[r] = exp2f((mrow[r] - mn) * L2E);
          mrow[r] = mn;
        }
      }
      float rs[4] = {0.f, 0.f, 0.f, 0.f};
#pragma unroll
      for (int ct = 0; ct < 4; ++ct)
#pragma unroll
        for (int r = 0; r < 4; ++r) {
          float p = exp2f((S[ct][r] - mrow[r]) * L2E);
          S[ct][r] = p;
          rs[r] += p;
        }
#pragma unroll
      for (int off = 1; off < 16; off <<= 1)
#pragma unroll
        for (int r = 0; r < 4; ++r) rs[r] += __shfl_xor(rs[r], off);
#pragma unroll
      for (int r = 0; r < 4; ++r)
        lrow[r] = skip ? (lrow[r] + rs[r]) : (lrow[r] * alpha[r] + rs[r]);
    }

    // ---- dropout (keepmask) + bf16 + wave-private LDS (C->A relayout) ----
#pragma unroll
    for (int r = 0; r < 4; ++r) {
      int prow = (lg * 4 + r) * PSTR + lm;
      Pw[prow +  0] = (bf16_t)(((km >> (0 + r)) & 1u)  ? S[0][r] : 0.f);
      Pw[prow + 16] = (bf16_t)(((km >> (4 + r)) & 1u)  ? S[1][r] : 0.f);
      Pw[prow + 32] = (bf16_t)(((km >> (8 + r)) & 1u)  ? S[2][r] : 0.f);
      Pw[prow + 48] = (bf16_t)(((km >> (12 + r)) & 1u) ? S[3][r] : 0.f);
    }
    asm volatile("s_waitcnt lgkmcnt(0)" ::: "memory");

    // ---- O = O*alpha + P V (V frags from LDS) ----
    if (!skip) {
#pragma unroll
      for (int c = 0; c < 8; ++c)
#pragma unroll
        for (int r = 0; r < 4; ++r) Oacc[c][r] *= alpha[r];
    }

    bf16x8 aP[2];
#pragma unroll
    for (int kk = 0; kk < 2; ++kk)
      aP[kk] = *(const bf16x8*)&Pw[lm * PSTR + kk * 32 + lg * 8];
#pragma unroll
    for (int c = 0; c < 8; ++c) {
      bf16x8 vf[2];
#pragma unroll
      for (int kk = 0; kk < 2; ++kk)
        vf[kk] = *(const bf16x8*)&Vs[(c * 16 + lm) * 64 + ((kk * 4 + lg) ^ (lm & 7)) * 8];
#pragma unroll
      for (int kk = 0; kk < 2; ++kk) Oacc[c] = mfma16(aP[kk], vf[kk], Oacc[c]);
    }
  }

  // ---- epilogue: normalize (1/l) * (1/0.9), write bf16 mid ----
  float invl[4];
#pragma unroll
  for (int r = 0; r < 4; ++r) invl[r] = (1.0f / 0.9f) / lrow[r];
#pragma unroll
  for (int c = 0; c < 8; ++c) {
    int d = c * 16 + lm;
#pragma unroll
    for (int r = 0; r < 4; ++r) {
      int bt = b * TLEN + row0 + lg * 4 + r;
      midb[(size_t)bt * DEMB + qh * 128 + d] = (bf16_t)(Oacc[c][r] * invl[r]);
    }
  }
}

// ---------------------------------------------------------------------------
extern "C" void kernel_launch(void* const* d_in, const int* in_sizes, int n_in,
                              void* d_out, int out_size, void* d_ws, size_t ws_size,
                              hipStream_t stream) {
  const float* x  = (const float*)d_in[0];
  const float* wq = (const float*)d_in[1];
  const float* wk = (const float*)d_in[2];
  const float* wv = (const float*)d_in[3];
  const float* wo = (const float*)d_in[4];
  float* out = (float*)d_out;
  float* kvc = out + ATTN_OUT_ELEMS;                    // [B,T,4,256] f32

  // workspace carve-up (~89.4 MB with separate maskbuf)
  char* ws = (char*)d_ws;
  bf16_t* Xb     = (bf16_t*)ws;                          ws += (size_t)4096 * 2048 * 2;  // 16.8MB
  bf16_t* Wqkvt  = (bf16_t*)ws;                          ws += (size_t)3072 * 2048 * 2;  // 12.6MB
  bf16_t* Wot    = (bf16_t*)ws;                          ws += (size_t)2048 * 2048 * 2;  // 8.4MB
  bf16_t* qbuf   = (bf16_t*)ws;                          ws += (size_t)2 * 16 * 2048 * 128 * 2; // 16.8MB
  bf16_t* Kbuf   = (bf16_t*)ws;                          ws += (size_t)2 * 4 * 2048 * 128 * 2;  // 4.2MB
  bf16_t* Vtb    = (bf16_t*)ws;                          ws += (size_t)2 * 4 * 128 * 2048 * 2;  // 4.2MB
  bf16_t* midb   = (bf16_t*)ws;                          ws += (size_t)4096 * 2048 * 2;  // 16.8MB
  float*  costab = (float*)ws;                           ws += (size_t)2048 * 64 * 4;    // 0.5MB
  float*  sintab = (float*)ws;                           ws += (size_t)2048 * 64 * 4;    // 0.5MB
  uint16_t* maskend = (uint16_t*)ws;                     // +8.65MB if available

  // Fused mode needs maskbuf DISJOINT from Xb (mask written during dispatches
  // that read Xb). If workspace is too small, fall back to the serial
  // standalone gen_mask (R1-known-good path) with maskbuf aliasing Xb.
  const size_t MASK_BYTES = (size_t)16896 * 256 * 2;     // 8.65MB
  const size_t need = (size_t)((char*)maskend - (char*)d_ws) + MASK_BYTES;
  const bool fused = ws_size >= need;
  uint16_t* maskbuf = fused ? maskend : (uint16_t*)Xb;

  dim3 blk(256);
  rope_tab<<<512, blk, 0, stream>>>(costab, sintab);

  // cvt: 8192 real (+416 appendix blocks, units [0,1664) @ 4/block)
  int cv_grid = fused ? 8192 + 416 : 8192;
  cvt_bf16<<<dim3(cv_grid), blk, 0, stream>>>(x, Xb, 8388608 / 4, maskbuf);

  // wtrans: 2560 real (+688 appendix blocks, units [1664,4416) @ 4/block)
  int wt_grid = fused ? 2560 + 688 : 2560;
  wtrans_all<<<dim3(wt_grid), blk, 0, stream>>>(wq, wk, wv, wo, Wqkvt, Wot, maskbuf);

  // QKV GEMM: 768 real (+1464 appendix blocks, units [5184,16896) @ 8/block)
  int g1_grid = fused ? 768 + 1464 : 768;
  gemm_bf16<1><<<dim3(g1_grid), blk, 0, stream>>>(Xb, Wqkvt, nullptr, qbuf, Kbuf, kvc,
                                                  costab, sintab, maskbuf,
                                                  4096, 3072, 2048);
  if (!fused)
    gen_mask<<<dim3(16896), blk, 0, stream>>>(maskbuf);

  // vtrans: 256 real (+192 appendix blocks, units [4416,5184) @ 4/block)
  int vt_grid = fused ? 256 + 192 : 256;
  vtrans<<<dim3(vt_grid), blk, 0, stream>>>(kvc, Vtb, maskbuf);

  attn_flash<<<dim3(1024), blk, 0, stream>>>(qbuf, Kbuf, Vtb, maskbuf, midb);
  gemm_bf16<0><<<dim3(512), blk, 0, stream>>>(midb, Wot, out, nullptr, nullptr, nullptr,
                                              nullptr, nullptr, nullptr,
                                              4096, 2048, 2048);
}

// Round 5
// 577.142 us; speedup vs baseline: 1.0479x; 1.0479x over previous
//
#include <hip/hip_runtime.h>
#include <stdint.h>

// Problem constants (fixed by reference)
#define BATCH 2
#define TLEN  2048
#define DEMB  2048
#define NHQ   16
#define NHKV  4
#define GRP   4
#define DKV   128
#define ATTN_OUT_ELEMS (BATCH*TLEN*DEMB) // 8388608
// d_out layout: [attn_output (8388608 f32) | kv_cache (B,T,4,256) f32 (4194304)]

typedef __bf16 bf16_t;
typedef __attribute__((ext_vector_type(4))) __bf16 bf16x4;
typedef __attribute__((ext_vector_type(8))) __bf16 bf16x8;
typedef __attribute__((ext_vector_type(4))) float f32x4;

__device__ __forceinline__ f32x4 mfma16(bf16x8 a, bf16x8 b, f32x4 c) {
  return __builtin_amdgcn_mfma_f32_16x16x32_bf16(a, b, c, 0, 0, 0);
}

typedef __attribute__((address_space(1))) const unsigned int as1_uint;
typedef __attribute__((address_space(3))) unsigned int as3_uint;
__device__ __forceinline__ void gload_lds16(const void* g, void* l) {
  // 16B per lane, LDS dest = l + lane*16 (wave-uniform base)
  __builtin_amdgcn_global_load_lds((as1_uint*)g, (as3_uint*)l, 16, 0, 0);
}

// ---------------------------------------------------------------------------
// threefry2x32-20, key=(0,1) (jax.random.key(1)), partitionable mode:
// per-element u64 counter (hi=0, lo=ctr), output = x0 ^ x1. Verified R1-R5.
// keep = uniform<0.9  <=>  bits < 0xE6666600 (bit-exact, verified R4/R5).
// NOTE (R1-R4 experiments): this VALU work (~124 machine-us) overlaps NOTHING
// wherever it is hosted (inline / standalone / GEMM-appendix all cost ~dense).
// Inline-in-attn is the cheapest home: zero extra dispatches and the compiler
// schedules it into the DMA-wait window.
// ---------------------------------------------------------------------------
__device__ __forceinline__ uint32_t rotl(uint32_t x, int r) {
  return __builtin_amdgcn_alignbit(x, x, 32 - r);
}
__device__ __forceinline__ void tf_round(uint32_t& x0, uint32_t& x1, int r) {
  x0 += x1;
  x1 = rotl(x1, r);
  x1 ^= x0;
}
__device__ __forceinline__ uint32_t threefry_bits(uint32_t ctr) {
  const uint32_t ks1 = 1u, ks2 = 0x1BD11BDBu;
  uint32_t x0 = 0u, x1 = ctr + ks1;
  tf_round(x0,x1,13); tf_round(x0,x1,15); tf_round(x0,x1,26); tf_round(x0,x1,6);
  x0 += ks1; x1 += ks2 + 1u;
  tf_round(x0,x1,17); tf_round(x0,x1,29); tf_round(x0,x1,16); tf_round(x0,x1,24);
  x0 += ks2; x1 += 0u + 2u;
  tf_round(x0,x1,13); tf_round(x0,x1,15); tf_round(x0,x1,26); tf_round(x0,x1,6);
  x0 += 0u;  x1 += ks1 + 3u;
  tf_round(x0,x1,17); tf_round(x0,x1,29); tf_round(x0,x1,16); tf_round(x0,x1,24);
  x0 += ks1; x1 += ks2 + 4u;
  tf_round(x0,x1,13); tf_round(x0,x1,15); tf_round(x0,x1,26); tf_round(x0,x1,6);
  x0 += ks2; x1 += 0u + 5u;
  return x0 ^ x1;
}

// ---------------------------------------------------------------------------
// fp32 -> bf16 convert (X) + RoPE cos/sin tables merged into one dispatch
// (both LDS-free; saves a launch). Blocks [0,8192): cvt; [8192,8704): tables.
// ---------------------------------------------------------------------------
__global__ __launch_bounds__(256) void cvt_rope(const float* __restrict__ src,
                                                bf16_t* __restrict__ dst,
                                                float* __restrict__ ct,
                                                float* __restrict__ st) {
  const int bid = blockIdx.x;
  if (bid >= 8192) {                           // RoPE tables [ti=2048][d=64]
    int i = (bid - 8192) * 256 + threadIdx.x;  // 131072 total
    int ti = i >> 6, d = i & 63;
    double theta = exp((double)(-2 * d) * (9.210340371976184 / 128.0)); // ln(1e4)/128
    float tick = (float)ti * (float)theta;
    ct[i] = (float)cos((double)tick);
    st[i] = (float)sin((double)tick);
    return;
  }
  int i = bid * 256 + threadIdx.x;             // 2097152 = 8192*256 exact
  float4 v = *(const float4*)(src + (size_t)i * 4);
  bf16x4 o = {(bf16_t)v.x, (bf16_t)v.y, (bf16_t)v.z, (bf16_t)v.w};
  *(bf16x4*)(dst + (size_t)i * 4) = o;
}

// ---------------------------------------------------------------------------
// Weight transpose+convert: src f32 [K][N] -> dst bf16 [N][Kd]; one dispatch
// covers wq/wk/wv/wo.
// ---------------------------------------------------------------------------
__device__ __forceinline__ void wtrans_body(const float* __restrict__ src,
                                            bf16_t* __restrict__ dst,
                                            int N, int Kd, int k0, int n0) {
  __shared__ float t[64][65];
  const int tid = threadIdx.x;
  const int r = tid >> 4, c4 = tid & 15;
#pragma unroll
  for (int i = 0; i < 4; ++i) {
    float4 v = *(const float4*)(src + (size_t)(k0 + r + i * 16) * N + n0 + c4 * 4);
    t[r + i * 16][c4 * 4 + 0] = v.x; t[r + i * 16][c4 * 4 + 1] = v.y;
    t[r + i * 16][c4 * 4 + 2] = v.z; t[r + i * 16][c4 * 4 + 3] = v.w;
  }
  __syncthreads();
#pragma unroll
  for (int i = 0; i < 4; ++i) {
    int idx = tid + i * 256;
    int rn = idx >> 4, ck = idx & 15;
    bf16x4 o = {(bf16_t)t[ck * 4 + 0][rn], (bf16_t)t[ck * 4 + 1][rn],
                (bf16_t)t[ck * 4 + 2][rn], (bf16_t)t[ck * 4 + 3][rn]};
    *(bf16x4*)(dst + (size_t)(n0 + rn) * Kd + k0 + ck * 4) = o;
  }
}

__global__ __launch_bounds__(256) void wtrans_all(const float* __restrict__ wq,
                                                  const float* __restrict__ wk,
                                                  const float* __restrict__ wv,
                                                  const float* __restrict__ wo,
                                                  bf16_t* __restrict__ dqkv,
                                                  bf16_t* __restrict__ dwo) {
  const int by = blockIdx.y, k0 = blockIdx.x * 64;
  if (by < 32)      wtrans_body(wq, dqkv,                        2048, 2048, k0, by * 64);
  else if (by < 40) wtrans_body(wk, dqkv + (size_t)2048 * 2048,  512,  2048, k0, (by - 32) * 64);
  else if (by < 48) wtrans_body(wv, dqkv + (size_t)2560 * 2048,  512,  2048, k0, (by - 40) * 64);
  else              wtrans_body(wo, dwo,                         2048, 2048, k0, (by - 48) * 64);
}

// ---------------------------------------------------------------------------
// bf16 MFMA GEMM: C[M,N] = Ab[M,K] (row-major) @ Wt[N,K]^T
// 128x128 tile, BK=64, 4 waves, 64x64/wave; col-tile pairing keeps RoPE
// partners (d, d+64) in-wave for MODE 1. global_load_lds(16B) staging with
// XOR chunk swizzle. MODE 0: f32 C. MODE 1: QKV epilogue (RoPE via tables).
// ---------------------------------------------------------------------------
template<int MODE>
__global__ __launch_bounds__(256) void gemm_bf16(
    const bf16_t* __restrict__ Ab, const bf16_t* __restrict__ Wt,
    float* __restrict__ Cout, bf16_t* __restrict__ qbuf,
    bf16_t* __restrict__ Kbuf, float* __restrict__ kvout,
    const float* __restrict__ costab, const float* __restrict__ sintab,
    int M, int N, int K) {
  __shared__ bf16_t As[128 * 64];
  __shared__ bf16_t Bs[128 * 64];
  const int tid = threadIdx.x;
  const int w = tid >> 6, lane = tid & 63;
  const int lm = lane & 15, lg = lane >> 4;
  const int wy = w & 1, wx = w >> 1;
  const int mblk = blockIdx.x * 128, nblk = blockIdx.y * 128;

  const int srow = lane >> 3;                 // row within 8-row group
  const int schunk = (lane & 7) ^ srow;       // fetch swizzled chunk
  const bf16_t* Ag = Ab + (size_t)(mblk + w * 32 + srow) * K + schunk * 8;
  const bf16_t* Bg = Wt + (size_t)(nblk + w * 32 + srow) * K + schunk * 8;
  bf16_t* AsW = As + (w * 32) * 64;
  bf16_t* BsW = Bs + (w * 32) * 64;

  f32x4 acc[4][4];
#pragma unroll
  for (int i = 0; i < 4; ++i)
#pragma unroll
    for (int j = 0; j < 4; ++j) acc[i][j] = (f32x4)0.0f;

  const int tcol0 = wx * 2;

  for (int k0 = 0; k0 < K; k0 += 64) {
    __syncthreads();
#pragma unroll
    for (int inst = 0; inst < 4; ++inst) {
      gload_lds16(Ag + (size_t)(inst * 8) * K + k0, AsW + inst * 8 * 64);
      gload_lds16(Bg + (size_t)(inst * 8) * K + k0, BsW + inst * 8 * 64);
    }
    asm volatile("s_waitcnt vmcnt(0)" ::: "memory");
    __syncthreads();
#pragma unroll
    for (int ks = 0; ks < 2; ++ks) {
      const int chunk = ((ks * 4 + lg) ^ (lane & 7)) * 8;
      bf16x8 af[4], bfr[4];
#pragma unroll
      for (int i = 0; i < 4; ++i) {
        int mrow = wy * 64 + i * 16 + lm;
        af[i] = *(const bf16x8*)&As[mrow * 64 + chunk];
      }
#pragma unroll
      for (int j = 0; j < 4; ++j) {
        int tc = tcol0 + (j & 1) + (j >> 1) * 4;
        int nrow = tc * 16 + lm;
        bfr[j] = *(const bf16x8*)&Bs[nrow * 64 + chunk];
      }
#pragma unroll
      for (int i = 0; i < 4; ++i)
#pragma unroll
        for (int j = 0; j < 4; ++j) acc[i][j] = mfma16(af[i], bfr[j], acc[i][j]);
    }
  }

  if (MODE == 0) {
#pragma unroll
    for (int i = 0; i < 4; ++i)
#pragma unroll
      for (int j = 0; j < 4; ++j) {
        int tc = tcol0 + (j & 1) + (j >> 1) * 4;
        int col = nblk + tc * 16 + lm;
#pragma unroll
        for (int r = 0; r < 4; ++r) {
          int row = mblk + wy * 64 + i * 16 + lg * 4 + r;
          Cout[(size_t)row * N + col] = acc[i][j][r];
        }
      }
  } else {
    // QKV epilogue with fused RoPE via tables. d in [0,64), partner d+64.
    const float qscale = 0.08838834764831843f;   // 1/sqrt(128)
#pragma unroll
    for (int i = 0; i < 4; ++i) {
#pragma unroll
      for (int r = 0; r < 4; ++r) {
        int row = mblk + wy * 64 + i * 16 + lg * 4 + r;   // bt
        int ti = row & (TLEN - 1), b = row >> 11;
#pragma unroll
        for (int jp = 0; jp < 2; ++jp) {
          float lo = acc[i][jp][r], hi = acc[i][jp + 2][r];
          int d = wx * 32 + jp * 16 + lm;                 // [0,64)
          int nl = nblk + d;                              // low-half global col
          if (nblk < 2048) {                              // q
            int qh = nl >> 7;
            float cs = costab[ti * 64 + d], sn = sintab[ti * 64 + d];
            float o0 = (lo * cs - hi * sn) * qscale;
            float o1 = (hi * cs + lo * sn) * qscale;
            size_t qo = (((size_t)(b * 16 + qh)) * TLEN + ti) * 128 + d;
            qbuf[qo] = (bf16_t)o0; qbuf[qo + 64] = (bf16_t)o1;
          } else if (nblk < 2560) {                       // k
            int hh = (nl - 2048) >> 7;
            float cs = costab[ti * 64 + d], sn = sintab[ti * 64 + d];
            float o0 = lo * cs - hi * sn;
            float o1 = hi * cs + lo * sn;
            size_t ko = (((size_t)(b * 4 + hh)) * TLEN + ti) * 128 + d;
            Kbuf[ko] = (bf16_t)o0; Kbuf[ko + 64] = (bf16_t)o1;
            size_t kvo = (size_t)row * 1024 + hh * 256 + d;
            kvout[kvo] = o0; kvout[kvo + 64] = o1;
          } else {                                        // v
            int hh = (nl - 2560) >> 7;
            size_t kvo = (size_t)row * 1024 + hh * 256 + 128 + d;
            kvout[kvo] = lo; kvout[kvo + 64] = hi;
          }
        }
      }
    }
  }
}

// ---------------------------------------------------------------------------
// V transpose: kv f32 [b][ti][h][128v @ +128] -> Vtb bf16 [b][h][d=128][tj=2048]
// ---------------------------------------------------------------------------
__global__ __launch_bounds__(256) void vtrans(const float* __restrict__ kvout,
                                              bf16_t* __restrict__ Vtb) {
  __shared__ bf16_t t[128][72];
  const int bx = blockIdx.x;          // (b*4+h)*32 + tt
  const int tt = bx & 31, bh = bx >> 5;
  const int b = bh >> 2, h = bh & 3;
  const int ti0 = tt * 64;
  const float* src = kvout + ((size_t)b * TLEN + ti0) * 1024 + h * 256 + 128;
  for (int idx = threadIdx.x; idx < 64 * 32; idx += 256) {
    int ti = idx >> 5, c4 = idx & 31;
    float4 v = *(const float4*)(src + (size_t)ti * 1024 + c4 * 4);
    t[c4 * 4 + 0][ti] = (bf16_t)v.x; t[c4 * 4 + 1][ti] = (bf16_t)v.y;
    t[c4 * 4 + 2][ti] = (bf16_t)v.z; t[c4 * 4 + 3][ti] = (bf16_t)v.w;
  }
  __syncthreads();
  bf16_t* dst = Vtb + (size_t)bh * 128 * TLEN + ti0;
  for (int idx = threadIdx.x; idx < 128 * 16; idx += 256) {
    int d = idx >> 4, ck = idx & 15;
    bf16x4 o = {t[d][ck * 4 + 0], t[d][ck * 4 + 1], t[d][ck * 4 + 2], t[d][ck * 4 + 3]};
    *(bf16x4*)(dst + (size_t)d * TLEN + ck * 4) = o;
  }
}

// ---------------------------------------------------------------------------
// Flash attention, bf16 MFMA. K LDS-staged (shared by 4 waves); V read
// DIRECTLY from L2-resident Vtb (8.4MB << L2+LLC) — dropping the Vs tile
// cuts LDS 41.5->25.6KB, raising occupancy 3->~5 blocks/CU, which is what
// the inline threefry needs to saturate VALU issue (guide mistake #7:
// LDS-staging L2-fit data is pure overhead). Inline threefry keepmask
// computed in the DMA-wait window (R1-R4: it never overlaps elsewhere).
// Online softmax via 16-lane shfl_xor, exact alpha-skip when no row max
// grows. P C->A relayout via wave-private LDS strip. qt<->31-qt pairing.
// ---------------------------------------------------------------------------
#define PSTR 68
__global__ __launch_bounds__(256, 4) void attn_flash(
    const bf16_t* __restrict__ qb, const bf16_t* __restrict__ Kb,
    const bf16_t* __restrict__ Vtb, bf16_t* __restrict__ midb) {
  __shared__ bf16_t Ks[64 * 128];    // [tj][d], 16B chunks XOR-swizzled by tj&15
  __shared__ bf16_t P_lds[64 * PSTR];
  const int tid = threadIdx.x;
  const int w = tid >> 6, lane = tid & 63;
  const int lm = lane & 15, lg = lane >> 4;

  const int bx = blockIdx.x;
  const int bhalf = bx >> 9, idx = bx & 511;
  const int bqh = idx & 31, t4 = idx >> 5;          // t4 in 0..15
  const int qt = bhalf ? (31 - t4) : t4;            // 0..31
  const int qh = bqh & 15, b = bqh >> 4;
  const int h = qh & 3, g = qh >> 2;

  const bf16_t* qbase = qb + (((size_t)(b * 16 + qh)) * TLEN + qt * 64 + w * 16) * 128;
  const bf16_t* kbase = Kb + ((size_t)(b * 4 + h)) * TLEN * 128;
  const bf16_t* vbase = Vtb + ((size_t)(b * 4 + h)) * 128 * TLEN;

  // K staging geometry (wave w stages K rows w*16..+15)
  const int krow_l = lane >> 4;              // 0..3 (4 rows per instr)
  const int kchunk = lane & 15;              // 16 chunks of 16B per 256B row
  const bf16_t* ksrc[4]; bf16_t* kdst[4];
#pragma unroll
  for (int j = 0; j < 4; ++j) {
    int klr = w * 16 + j * 4 + krow_l;       // tile-local K row
    ksrc[j] = kbase + (size_t)klr * 128 + (size_t)((kchunk ^ (j * 4 + krow_l)) * 8);
    kdst[j] = Ks + (w * 16 + j * 4) * 128;
  }
  // direct-V per-lane base: row d = c*16+lm, k-chunk (kk*4+lg)*8 -> +tj0+c,kk
  const bf16_t* vlane = vbase + (size_t)lm * TLEN + lg * 8;

  // Q A-frags (16 rows); q already scaled by 1/sqrt(128)
  bf16x8 qf[4];
#pragma unroll
  for (int kk = 0; kk < 4; ++kk)
    qf[kk] = *(const bf16x8*)(qbase + (size_t)lm * 128 + kk * 32 + lg * 8);

  float mrow[4], lrow[4];
  f32x4 Oacc[8];
#pragma unroll
  for (int r = 0; r < 4; ++r) { mrow[r] = -3.0e38f; lrow[r] = 0.f; }
#pragma unroll
  for (int c = 0; c < 8; ++c) Oacc[c] = (f32x4)0.0f;

  const int row0 = qt * 64 + w * 16;           // wave's first q row
  const int nkt = qt + 1;                      // K-tiles (uniform across waves)
  const float L2E = 1.4426950408889634f;
  const uint32_t hdr = (uint32_t)((b * 4 + g) * 4 + h);
  bf16_t* Pw = P_lds + (w * 16) * PSTR;

  for (int kt = 0; kt < nkt; ++kt) {
    const int tj0 = kt * 64;
    __syncthreads();                           // prev iter's Ks reads done
    // ---- async stage K tile (4 DMA instrs per wave) ----
#pragma unroll
    for (int j = 0; j < 4; ++j) gload_lds16(ksrc[j] + (size_t)tj0 * 128, kdst[j]);

    // ---- threefry keepmask for this tile (fills the DMA-wait window) ----
    uint32_t km = 0;
#pragma unroll
    for (int r = 0; r < 4; ++r) {
      uint32_t cb = (hdr << 22) + ((uint32_t)(row0 + lg * 4 + r) << 11)
                  + (uint32_t)(tj0 + lm);
#pragma unroll
      for (int ct = 0; ct < 4; ++ct) {
        uint32_t bits = threefry_bits(cb + (uint32_t)(ct * 16));
        km |= (bits < 0xE6666600u ? 1u : 0u) << (ct * 4 + r);
      }
    }
    asm volatile("s_waitcnt vmcnt(0)" ::: "memory");
    __syncthreads();                           // K tile visible to all waves

    // ---- S = Q K^T (K frags from LDS) ----
    f32x4 S[4];
#pragma unroll
    for (int ct = 0; ct < 4; ++ct) {
      S[ct] = (f32x4)0.0f;
      bf16x8 kf[4];
#pragma unroll
      for (int kk = 0; kk < 4; ++kk)
        kf[kk] = *(const bf16x8*)&Ks[(ct * 16 + lm) * 128 + ((kk * 4 + lg) ^ lm) * 8];
#pragma unroll
      for (int kk = 0; kk < 4; ++kk) S[ct] = mfma16(qf[kk], kf[kk], S[ct]);
    }

    // ---- causal mask (diagonal tile only) ----
    if (tj0 + 63 > row0) {
#pragma unroll
      for (int ct = 0; ct < 4; ++ct) {
        int tj = tj0 + ct * 16 + lm;
#pragma unroll
        for (int r = 0; r < 4; ++r) {
          int ti = row0 + lg * 4 + r;
          if (tj > ti) S[ct][r] = -1.0e30f;
        }
      }
    }

    // ---- online softmax (exact alpha-skip when no row max grows) ----
    float alpha[4];
    bool skip;
    {
      float pm[4];
#pragma unroll
      for (int r = 0; r < 4; ++r)
        pm[r] = fmaxf(fmaxf(S[0][r], S[1][r]), fmaxf(S[2][r], S[3][r]));
#pragma unroll
      for (int off = 1; off < 16; off <<= 1)
#pragma unroll
        for (int r = 0; r < 4; ++r) pm[r] = fmaxf(pm[r], __shfl_xor(pm[r], off));
      bool nu = (pm[0] <= mrow[0]) & (pm[1] <= mrow[1]) &
                (pm[2] <= mrow[2]) & (pm[3] <= mrow[3]);
      skip = __all(nu);
      if (!skip) {
#pragma unroll
        for (int r = 0; r < 4; ++r) {
          float mn = fmaxf(mrow[r], pm[r]);
          alpha[r] = exp2f((mrow[r] - mn) * L2E);
          mrow[r] = mn;
        }
      }
      float rs[4] = {0.f, 0.f, 0.f, 0.f};
#pragma unroll
      for (int ct = 0; ct < 4; ++ct)
#pragma unroll
        for (int r = 0; r < 4; ++r) {
          float p = exp2f((S[ct][r] - mrow[r]) * L2E);
          S[ct][r] = p;
          rs[r] += p;
        }
#pragma unroll
      for (int off = 1; off < 16; off <<= 1)
#pragma unroll
        for (int r = 0; r < 4; ++r) rs[r] += __shfl_xor(rs[r], off);
#pragma unroll
      for (int r = 0; r < 4; ++r)
        lrow[r] = skip ? (lrow[r] + rs[r]) : (lrow[r] * alpha[r] + rs[r]);
    }

    // ---- dropout (keepmask) + bf16 + wave-private LDS (C->A relayout) ----
#pragma unroll
    for (int r = 0; r < 4; ++r) {
      int prow = (lg * 4 + r) * PSTR + lm;
      Pw[prow +  0] = (bf16_t)(((km >> (0 + r)) & 1u)  ? S[0][r] : 0.f);
      Pw[prow + 16] = (bf16_t)(((km >> (4 + r)) & 1u)  ? S[1][r] : 0.f);
      Pw[prow + 32] = (bf16_t)(((km >> (8 + r)) & 1u)  ? S[2][r] : 0.f);
      Pw[prow + 48] = (bf16_t)(((km >> (12 + r)) & 1u) ? S[3][r] : 0.f);
    }
    asm volatile("s_waitcnt lgkmcnt(0)" ::: "memory");

    // ---- O = O*alpha + P V (V frags DIRECT from L2-resident Vtb) ----
    if (!skip) {
#pragma unroll
      for (int c = 0; c < 8; ++c)
#pragma unroll
        for (int r = 0; r < 4; ++r) Oacc[c][r] *= alpha[r];
    }

    bf16x8 aP[2];
#pragma unroll
    for (int kk = 0; kk < 2; ++kk)
      aP[kk] = *(const bf16x8*)&Pw[lm * PSTR + kk * 32 + lg * 8];
    const bf16_t* vt = vlane + tj0;
#pragma unroll
    for (int c = 0; c < 8; ++c) {
      bf16x8 vf0 = *(const bf16x8*)(vt + (size_t)(c * 16) * TLEN);
      bf16x8 vf1 = *(const bf16x8*)(vt + (size_t)(c * 16) * TLEN + 32);
      Oacc[c] = mfma16(aP[0], vf0, Oacc[c]);
      Oacc[c] = mfma16(aP[1], vf1, Oacc[c]);
    }
  }

  // ---- epilogue: normalize (1/l) * (1/0.9), write bf16 mid ----
  float invl[4];
#pragma unroll
  for (int r = 0; r < 4; ++r) invl[r] = (1.0f / 0.9f) / lrow[r];
#pragma unroll
  for (int c = 0; c < 8; ++c) {
    int d = c * 16 + lm;
#pragma unroll
    for (int r = 0; r < 4; ++r) {
      int bt = b * TLEN + row0 + lg * 4 + r;
      midb[(size_t)bt * DEMB + qh * 128 + d] = (bf16_t)(Oacc[c][r] * invl[r]);
    }
  }
}

// ---------------------------------------------------------------------------
extern "C" void kernel_launch(void* const* d_in, const int* in_sizes, int n_in,
                              void* d_out, int out_size, void* d_ws, size_t ws_size,
                              hipStream_t stream) {
  const float* x  = (const float*)d_in[0];
  const float* wq = (const float*)d_in[1];
  const float* wk = (const float*)d_in[2];
  const float* wv = (const float*)d_in[3];
  const float* wo = (const float*)d_in[4];
  float* out = (float*)d_out;
  float* kvc = out + ATTN_OUT_ELEMS;                    // [B,T,4,256] f32

  // workspace carve-up (~80.8 MB)
  char* ws = (char*)d_ws;
  bf16_t* Xb     = (bf16_t*)ws;                          ws += (size_t)4096 * 2048 * 2;  // 16.8MB
  bf16_t* Wqkvt  = (bf16_t*)ws;                          ws += (size_t)3072 * 2048 * 2;  // 12.6MB
  bf16_t* Wot    = (bf16_t*)ws;                          ws += (size_t)2048 * 2048 * 2;  // 8.4MB
  bf16_t* qbuf   = (bf16_t*)ws;                          ws += (size_t)2 * 16 * 2048 * 128 * 2; // 16.8MB
  bf16_t* Kbuf   = (bf16_t*)ws;                          ws += (size_t)2 * 4 * 2048 * 128 * 2;  // 4.2MB
  bf16_t* Vtb    = (bf16_t*)ws;                          ws += (size_t)2 * 4 * 128 * 2048 * 2;  // 4.2MB
  bf16_t* midb   = (bf16_t*)ws;                          ws += (size_t)4096 * 2048 * 2;  // 16.8MB
  float*  costab = (float*)ws;                           ws += (size_t)2048 * 64 * 4;    // 0.5MB
  float*  sintab = (float*)ws;                           // 0.5MB

  dim3 blk(256);
  cvt_rope<<<dim3(8704), blk, 0, stream>>>(x, Xb, costab, sintab);
  wtrans_all<<<dim3(32, 80), blk, 0, stream>>>(wq, wk, wv, wo, Wqkvt, Wot);

  gemm_bf16<1><<<dim3(32, 24), blk, 0, stream>>>(Xb, Wqkvt, nullptr, qbuf, Kbuf, kvc,
                                                 costab, sintab, 4096, 3072, 2048);
  vtrans<<<dim3(256), blk, 0, stream>>>(kvc, Vtb);
  attn_flash<<<dim3(1024), blk, 0, stream>>>(qbuf, Kbuf, Vtb, midb);
  gemm_bf16<0><<<dim3(32, 16), blk, 0, stream>>>(midb, Wot, out, nullptr, nullptr, nullptr,
                                                 nullptr, nullptr, 4096, 2048, 2048);
}

// Round 6
// 467.381 us; speedup vs baseline: 1.2940x; 1.2348x over previous
//
#include <hip/hip_runtime.h>
#include <stdint.h>

// Problem constants (fixed by reference)
#define BATCH 2
#define TLEN  2048
#define DEMB  2048
#define NHQ   16
#define NHKV  4
#define GRP   4
#define DKV   128
#define ATTN_OUT_ELEMS (BATCH*TLEN*DEMB) // 8388608
// d_out layout: [attn_output (8388608 f32) | kv_cache (B,T,4,256) f32 (4194304)]

typedef __bf16 bf16_t;
typedef __attribute__((ext_vector_type(4))) __bf16 bf16x4;
typedef __attribute__((ext_vector_type(8))) __bf16 bf16x8;
typedef __attribute__((ext_vector_type(4))) float f32x4;

__device__ __forceinline__ f32x4 mfma16(bf16x8 a, bf16x8 b, f32x4 c) {
  return __builtin_amdgcn_mfma_f32_16x16x32_bf16(a, b, c, 0, 0, 0);
}

typedef __attribute__((address_space(1))) const unsigned int as1_uint;
typedef __attribute__((address_space(3))) unsigned int as3_uint;
__device__ __forceinline__ void gload_lds16(const void* g, void* l) {
  // 16B per lane, LDS dest = l + lane*16 (wave-uniform base)
  __builtin_amdgcn_global_load_lds((as1_uint*)g, (as3_uint*)l, 16, 0, 0);
}

// ---------------------------------------------------------------------------
// threefry2x32-20, key=(0,1) (jax.random.key(1)), partitionable mode:
// per-element u64 counter (hi=0, lo=ctr), output = x0 ^ x1. Verified R1-R5.
// keep = uniform<0.9  <=>  bits < 0xE6666600 (bit-exact, verified R4/R5).
// NOTE (R1-R4 experiments): this VALU work (~124 machine-us) overlaps NOTHING
// wherever it is hosted (inline / standalone / GEMM-appendix all cost ~dense).
// Inline-in-attn is the cheapest home; the lever is attn's own occupancy.
// ---------------------------------------------------------------------------
__device__ __forceinline__ uint32_t rotl(uint32_t x, int r) {
  return __builtin_amdgcn_alignbit(x, x, 32 - r);
}
__device__ __forceinline__ void tf_round(uint32_t& x0, uint32_t& x1, int r) {
  x0 += x1;
  x1 = rotl(x1, r);
  x1 ^= x0;
}
__device__ __forceinline__ uint32_t threefry_bits(uint32_t ctr) {
  const uint32_t ks1 = 1u, ks2 = 0x1BD11BDBu;
  uint32_t x0 = 0u, x1 = ctr + ks1;
  tf_round(x0,x1,13); tf_round(x0,x1,15); tf_round(x0,x1,26); tf_round(x0,x1,6);
  x0 += ks1; x1 += ks2 + 1u;
  tf_round(x0,x1,17); tf_round(x0,x1,29); tf_round(x0,x1,16); tf_round(x0,x1,24);
  x0 += ks2; x1 += 0u + 2u;
  tf_round(x0,x1,13); tf_round(x0,x1,15); tf_round(x0,x1,26); tf_round(x0,x1,6);
  x0 += 0u;  x1 += ks1 + 3u;
  tf_round(x0,x1,17); tf_round(x0,x1,29); tf_round(x0,x1,16); tf_round(x0,x1,24);
  x0 += ks1; x1 += ks2 + 4u;
  tf_round(x0,x1,13); tf_round(x0,x1,15); tf_round(x0,x1,26); tf_round(x0,x1,6);
  x0 += ks2; x1 += 0u + 5u;
  return x0 ^ x1;
}

// ---------------------------------------------------------------------------
// fp32 -> bf16 convert (X) + RoPE cos/sin tables merged into one dispatch
// (both LDS-free; saves a launch). Blocks [0,8192): cvt; [8192,8704): tables.
// ---------------------------------------------------------------------------
__global__ __launch_bounds__(256) void cvt_rope(const float* __restrict__ src,
                                                bf16_t* __restrict__ dst,
                                                float* __restrict__ ct,
                                                float* __restrict__ st) {
  const int bid = blockIdx.x;
  if (bid >= 8192) {                           // RoPE tables [ti=2048][d=64]
    int i = (bid - 8192) * 256 + threadIdx.x;  // 131072 total
    int ti = i >> 6, d = i & 63;
    double theta = exp((double)(-2 * d) * (9.210340371976184 / 128.0)); // ln(1e4)/128
    float tick = (float)ti * (float)theta;
    ct[i] = (float)cos((double)tick);
    st[i] = (float)sin((double)tick);
    return;
  }
  int i = bid * 256 + threadIdx.x;             // 2097152 = 8192*256 exact
  float4 v = *(const float4*)(src + (size_t)i * 4);
  bf16x4 o = {(bf16_t)v.x, (bf16_t)v.y, (bf16_t)v.z, (bf16_t)v.w};
  *(bf16x4*)(dst + (size_t)i * 4) = o;
}

// ---------------------------------------------------------------------------
// Weight transpose+convert: src f32 [K][N] -> dst bf16 [N][Kd]; one dispatch
// covers wq/wk/wv/wo.
// ---------------------------------------------------------------------------
__device__ __forceinline__ void wtrans_body(const float* __restrict__ src,
                                            bf16_t* __restrict__ dst,
                                            int N, int Kd, int k0, int n0) {
  __shared__ float t[64][65];
  const int tid = threadIdx.x;
  const int r = tid >> 4, c4 = tid & 15;
#pragma unroll
  for (int i = 0; i < 4; ++i) {
    float4 v = *(const float4*)(src + (size_t)(k0 + r + i * 16) * N + n0 + c4 * 4);
    t[r + i * 16][c4 * 4 + 0] = v.x; t[r + i * 16][c4 * 4 + 1] = v.y;
    t[r + i * 16][c4 * 4 + 2] = v.z; t[r + i * 16][c4 * 4 + 3] = v.w;
  }
  __syncthreads();
#pragma unroll
  for (int i = 0; i < 4; ++i) {
    int idx = tid + i * 256;
    int rn = idx >> 4, ck = idx & 15;
    bf16x4 o = {(bf16_t)t[ck * 4 + 0][rn], (bf16_t)t[ck * 4 + 1][rn],
                (bf16_t)t[ck * 4 + 2][rn], (bf16_t)t[ck * 4 + 3][rn]};
    *(bf16x4*)(dst + (size_t)(n0 + rn) * Kd + k0 + ck * 4) = o;
  }
}

__global__ __launch_bounds__(256) void wtrans_all(const float* __restrict__ wq,
                                                  const float* __restrict__ wk,
                                                  const float* __restrict__ wv,
                                                  const float* __restrict__ wo,
                                                  bf16_t* __restrict__ dqkv,
                                                  bf16_t* __restrict__ dwo) {
  const int by = blockIdx.y, k0 = blockIdx.x * 64;
  if (by < 32)      wtrans_body(wq, dqkv,                        2048, 2048, k0, by * 64);
  else if (by < 40) wtrans_body(wk, dqkv + (size_t)2048 * 2048,  512,  2048, k0, (by - 32) * 64);
  else if (by < 48) wtrans_body(wv, dqkv + (size_t)2560 * 2048,  512,  2048, k0, (by - 40) * 64);
  else              wtrans_body(wo, dwo,                         2048, 2048, k0, (by - 48) * 64);
}

// ---------------------------------------------------------------------------
// bf16 MFMA GEMM: C[M,N] = Ab[M,K] (row-major) @ Wt[N,K]^T
// 128x128 tile, BK=64, 4 waves, 64x64/wave; col-tile pairing keeps RoPE
// partners (d, d+64) in-wave for MODE 1. global_load_lds(16B) staging with
// XOR chunk swizzle. MODE 0: f32 C. MODE 1: QKV epilogue (RoPE via tables).
// ---------------------------------------------------------------------------
template<int MODE>
__global__ __launch_bounds__(256) void gemm_bf16(
    const bf16_t* __restrict__ Ab, const bf16_t* __restrict__ Wt,
    float* __restrict__ Cout, bf16_t* __restrict__ qbuf,
    bf16_t* __restrict__ Kbuf, float* __restrict__ kvout,
    const float* __restrict__ costab, const float* __restrict__ sintab,
    int M, int N, int K) {
  __shared__ bf16_t As[128 * 64];
  __shared__ bf16_t Bs[128 * 64];
  const int tid = threadIdx.x;
  const int w = tid >> 6, lane = tid & 63;
  const int lm = lane & 15, lg = lane >> 4;
  const int wy = w & 1, wx = w >> 1;
  const int mblk = blockIdx.x * 128, nblk = blockIdx.y * 128;

  const int srow = lane >> 3;                 // row within 8-row group
  const int schunk = (lane & 7) ^ srow;       // fetch swizzled chunk
  const bf16_t* Ag = Ab + (size_t)(mblk + w * 32 + srow) * K + schunk * 8;
  const bf16_t* Bg = Wt + (size_t)(nblk + w * 32 + srow) * K + schunk * 8;
  bf16_t* AsW = As + (w * 32) * 64;
  bf16_t* BsW = Bs + (w * 32) * 64;

  f32x4 acc[4][4];
#pragma unroll
  for (int i = 0; i < 4; ++i)
#pragma unroll
    for (int j = 0; j < 4; ++j) acc[i][j] = (f32x4)0.0f;

  const int tcol0 = wx * 2;

  for (int k0 = 0; k0 < K; k0 += 64) {
    __syncthreads();
#pragma unroll
    for (int inst = 0; inst < 4; ++inst) {
      gload_lds16(Ag + (size_t)(inst * 8) * K + k0, AsW + inst * 8 * 64);
      gload_lds16(Bg + (size_t)(inst * 8) * K + k0, BsW + inst * 8 * 64);
    }
    asm volatile("s_waitcnt vmcnt(0)" ::: "memory");
    __syncthreads();
#pragma unroll
    for (int ks = 0; ks < 2; ++ks) {
      const int chunk = ((ks * 4 + lg) ^ (lane & 7)) * 8;
      bf16x8 af[4], bfr[4];
#pragma unroll
      for (int i = 0; i < 4; ++i) {
        int mrow = wy * 64 + i * 16 + lm;
        af[i] = *(const bf16x8*)&As[mrow * 64 + chunk];
      }
#pragma unroll
      for (int j = 0; j < 4; ++j) {
        int tc = tcol0 + (j & 1) + (j >> 1) * 4;
        int nrow = tc * 16 + lm;
        bfr[j] = *(const bf16x8*)&Bs[nrow * 64 + chunk];
      }
#pragma unroll
      for (int i = 0; i < 4; ++i)
#pragma unroll
        for (int j = 0; j < 4; ++j) acc[i][j] = mfma16(af[i], bfr[j], acc[i][j]);
    }
  }

  if (MODE == 0) {
#pragma unroll
    for (int i = 0; i < 4; ++i)
#pragma unroll
      for (int j = 0; j < 4; ++j) {
        int tc = tcol0 + (j & 1) + (j >> 1) * 4;
        int col = nblk + tc * 16 + lm;
#pragma unroll
        for (int r = 0; r < 4; ++r) {
          int row = mblk + wy * 64 + i * 16 + lg * 4 + r;
          Cout[(size_t)row * N + col] = acc[i][j][r];
        }
      }
  } else {
    // QKV epilogue with fused RoPE via tables. d in [0,64), partner d+64.
    const float qscale = 0.08838834764831843f;   // 1/sqrt(128)
#pragma unroll
    for (int i = 0; i < 4; ++i) {
#pragma unroll
      for (int r = 0; r < 4; ++r) {
        int row = mblk + wy * 64 + i * 16 + lg * 4 + r;   // bt
        int ti = row & (TLEN - 1), b = row >> 11;
#pragma unroll
        for (int jp = 0; jp < 2; ++jp) {
          float lo = acc[i][jp][r], hi = acc[i][jp + 2][r];
          int d = wx * 32 + jp * 16 + lm;                 // [0,64)
          int nl = nblk + d;                              // low-half global col
          if (nblk < 2048) {                              // q
            int qh = nl >> 7;
            float cs = costab[ti * 64 + d], sn = sintab[ti * 64 + d];
            float o0 = (lo * cs - hi * sn) * qscale;
            float o1 = (hi * cs + lo * sn) * qscale;
            size_t qo = (((size_t)(b * 16 + qh)) * TLEN + ti) * 128 + d;
            qbuf[qo] = (bf16_t)o0; qbuf[qo + 64] = (bf16_t)o1;
          } else if (nblk < 2560) {                       // k
            int hh = (nl - 2048) >> 7;
            float cs = costab[ti * 64 + d], sn = sintab[ti * 64 + d];
            float o0 = lo * cs - hi * sn;
            float o1 = hi * cs + lo * sn;
            size_t ko = (((size_t)(b * 4 + hh)) * TLEN + ti) * 128 + d;
            Kbuf[ko] = (bf16_t)o0; Kbuf[ko + 64] = (bf16_t)o1;
            size_t kvo = (size_t)row * 1024 + hh * 256 + d;
            kvout[kvo] = o0; kvout[kvo + 64] = o1;
          } else {                                        // v
            int hh = (nl - 2560) >> 7;
            size_t kvo = (size_t)row * 1024 + hh * 256 + 128 + d;
            kvout[kvo] = lo; kvout[kvo + 64] = hi;
          }
        }
      }
    }
  }
}

// ---------------------------------------------------------------------------
// V transpose: kv f32 [b][ti][h][128v @ +128] -> Vtb bf16 [b][h][d=128][tj=2048]
// ---------------------------------------------------------------------------
__global__ __launch_bounds__(256) void vtrans(const float* __restrict__ kvout,
                                              bf16_t* __restrict__ Vtb) {
  __shared__ bf16_t t[128][72];
  const int bx = blockIdx.x;          // (b*4+h)*32 + tt
  const int tt = bx & 31, bh = bx >> 5;
  const int b = bh >> 2, h = bh & 3;
  const int ti0 = tt * 64;
  const float* src = kvout + ((size_t)b * TLEN + ti0) * 1024 + h * 256 + 128;
  for (int idx = threadIdx.x; idx < 64 * 32; idx += 256) {
    int ti = idx >> 5, c4 = idx & 31;
    float4 v = *(const float4*)(src + (size_t)ti * 1024 + c4 * 4);
    t[c4 * 4 + 0][ti] = (bf16_t)v.x; t[c4 * 4 + 1][ti] = (bf16_t)v.y;
    t[c4 * 4 + 2][ti] = (bf16_t)v.z; t[c4 * 4 + 3][ti] = (bf16_t)v.w;
  }
  __syncthreads();
  bf16_t* dst = Vtb + (size_t)bh * 128 * TLEN + ti0;
  for (int idx = threadIdx.x; idx < 128 * 16; idx += 256) {
    int d = idx >> 4, ck = idx & 15;
    bf16x4 o = {t[d][ck * 4 + 0], t[d][ck * 4 + 1], t[d][ck * 4 + 2], t[d][ck * 4 + 3]};
    *(bf16x4*)(dst + (size_t)d * TLEN + ck * 4) = o;
  }
}

// ---------------------------------------------------------------------------
// Flash attention, bf16 MFMA. K and V TIME-SHARE one 16KB LDS buffer (both
// tiles are exactly 64x128 bf16; consumed in disjoint phases QK^T / PV).
// Per tile: K-DMA -> threefry (hides K latency) -> bar -> QK^T -> bar ->
// V-DMA into same buffer -> softmax (hides V latency) -> bar -> PV.
// LDS 41.5->25.1KB lifts occupancy 3->4 blocks/CU (VGPR-84 limit), raising
// VALU busy on the irreducible inline threefry (R5 lesson: direct-V reads
// miss L2 cross-XCD and over-fetch; V must stay LDS-staged and coalesced).
// Online softmax via 16-lane shfl_xor; exact alpha-skip. qt<->31-qt pairing.
// ---------------------------------------------------------------------------
#define PSTR 68
__global__ __launch_bounds__(256, 3) void attn_flash(
    const bf16_t* __restrict__ qb, const bf16_t* __restrict__ Kb,
    const bf16_t* __restrict__ Vtb, bf16_t* __restrict__ midb) {
  __shared__ bf16_t KVs[64 * 128];   // K: [tj][d] / V: [d][tj], time-shared
  __shared__ bf16_t P_lds[64 * PSTR];
  const int tid = threadIdx.x;
  const int w = tid >> 6, lane = tid & 63;
  const int lm = lane & 15, lg = lane >> 4;

  const int bx = blockIdx.x;
  const int bhalf = bx >> 9, idx = bx & 511;
  const int bqh = idx & 31, t4 = idx >> 5;          // t4 in 0..15
  const int qt = bhalf ? (31 - t4) : t4;            // 0..31
  const int qh = bqh & 15, b = bqh >> 4;
  const int h = qh & 3, g = qh >> 2;

  const bf16_t* qbase = qb + (((size_t)(b * 16 + qh)) * TLEN + qt * 64 + w * 16) * 128;
  const bf16_t* kbase = Kb + ((size_t)(b * 4 + h)) * TLEN * 128;
  const bf16_t* vbase = Vtb + ((size_t)(b * 4 + h)) * 128 * TLEN;

  // staging geometry (wave w stages K rows w*16..+15, V rows w*32..+31)
  const int krow_l = lane >> 4;              // 0..3 (4 rows per instr)
  const int kchunk = lane & 15;              // 16 chunks of 16B per 256B row
  const int vrow_l = lane >> 3;              // 0..7 (8 rows per instr)
  const int vchunk = (lane & 7) ^ (vrow_l & 7);
  const bf16_t* ksrc[4]; const bf16_t* vsrc[4];
  bf16_t* kdst[4]; bf16_t* vdst[4];
#pragma unroll
  for (int j = 0; j < 4; ++j) {
    int klr = w * 16 + j * 4 + krow_l;       // tile-local K row
    ksrc[j] = kbase + (size_t)klr * 128 + (size_t)((kchunk ^ (j * 4 + krow_l)) * 8);
    kdst[j] = KVs + (w * 16 + j * 4) * 128;
    int vd = w * 32 + j * 8 + vrow_l;        // V row (d)
    vsrc[j] = vbase + (size_t)vd * TLEN + (size_t)(vchunk * 8);
    vdst[j] = KVs + (w * 32 + j * 8) * 64;
  }

  // Q A-frags (16 rows); q already scaled by 1/sqrt(128)
  bf16x8 qf[4];
#pragma unroll
  for (int kk = 0; kk < 4; ++kk)
    qf[kk] = *(const bf16x8*)(qbase + (size_t)lm * 128 + kk * 32 + lg * 8);

  float mrow[4], lrow[4];
  f32x4 Oacc[8];
#pragma unroll
  for (int r = 0; r < 4; ++r) { mrow[r] = -3.0e38f; lrow[r] = 0.f; }
#pragma unroll
  for (int c = 0; c < 8; ++c) Oacc[c] = (f32x4)0.0f;

  const int row0 = qt * 64 + w * 16;           // wave's first q row
  const int nkt = qt + 1;                      // K-tiles (uniform across waves)
  const float L2E = 1.4426950408889634f;
  const uint32_t hdr = (uint32_t)((b * 4 + g) * 4 + h);
  bf16_t* Pw = P_lds + (w * 16) * PSTR;

  for (int kt = 0; kt < nkt; ++kt) {
    const int tj0 = kt * 64;
    __syncthreads();                           // prev iter's PV reads done
    // ---- async stage K tile (4 DMA instrs per wave) ----
#pragma unroll
    for (int j = 0; j < 4; ++j) gload_lds16(ksrc[j] + (size_t)tj0 * 128, kdst[j]);

    // ---- threefry keepmask for this tile (fills the K-DMA window) ----
    uint32_t km = 0;
#pragma unroll
    for (int r = 0; r < 4; ++r) {
      uint32_t cb = (hdr << 22) + ((uint32_t)(row0 + lg * 4 + r) << 11)
                  + (uint32_t)(tj0 + lm);
#pragma unroll
      for (int ct = 0; ct < 4; ++ct) {
        uint32_t bits = threefry_bits(cb + (uint32_t)(ct * 16));
        km |= (bits < 0xE6666600u ? 1u : 0u) << (ct * 4 + r);
      }
    }
    asm volatile("s_waitcnt vmcnt(0)" ::: "memory");
    __syncthreads();                           // K tile visible to all waves

    // ---- S = Q K^T (K frags from LDS) ----
    f32x4 S[4];
#pragma unroll
    for (int ct = 0; ct < 4; ++ct) {
      S[ct] = (f32x4)0.0f;
      bf16x8 kf[4];
#pragma unroll
      for (int kk = 0; kk < 4; ++kk)
        kf[kk] = *(const bf16x8*)&KVs[(ct * 16 + lm) * 128 + ((kk * 4 + lg) ^ lm) * 8];
#pragma unroll
      for (int kk = 0; kk < 4; ++kk) S[ct] = mfma16(qf[kk], kf[kk], S[ct]);
    }

    __syncthreads();                           // all waves done reading K
    // ---- async stage V tile into the SAME buffer ----
#pragma unroll
    for (int j = 0; j < 4; ++j) gload_lds16(vsrc[j] + tj0, vdst[j]);

    // ---- causal mask (diagonal tile only) ----
    if (tj0 + 63 > row0) {
#pragma unroll
      for (int ct = 0; ct < 4; ++ct) {
        int tj = tj0 + ct * 16 + lm;
#pragma unroll
        for (int r = 0; r < 4; ++r) {
          int ti = row0 + lg * 4 + r;
          if (tj > ti) S[ct][r] = -1.0e30f;
        }
      }
    }

    // ---- online softmax (exact alpha-skip; fills the V-DMA window) ----
    float alpha[4];
    bool skip;
    {
      float pm[4];
#pragma unroll
      for (int r = 0; r < 4; ++r)
        pm[r] = fmaxf(fmaxf(S[0][r], S[1][r]), fmaxf(S[2][r], S[3][r]));
#pragma unroll
      for (int off = 1; off < 16; off <<= 1)
#pragma unroll
        for (int r = 0; r < 4; ++r) pm[r] = fmaxf(pm[r], __shfl_xor(pm[r], off));
      bool nu = (pm[0] <= mrow[0]) & (pm[1] <= mrow[1]) &
                (pm[2] <= mrow[2]) & (pm[3] <= mrow[3]);
      skip = __all(nu);
      if (!skip) {
#pragma unroll
        for (int r = 0; r < 4; ++r) {
          float mn = fmaxf(mrow[r], pm[r]);
          alpha[r] = exp2f((mrow[r] - mn) * L2E);
          mrow[r] = mn;
        }
      }
      float rs[4] = {0.f, 0.f, 0.f, 0.f};
#pragma unroll
      for (int ct = 0; ct < 4; ++ct)
#pragma unroll
        for (int r = 0; r < 4; ++r) {
          float p = exp2f((S[ct][r] - mrow[r]) * L2E);
          S[ct][r] = p;
          rs[r] += p;
        }
#pragma unroll
      for (int off = 1; off < 16; off <<= 1)
#pragma unroll
        for (int r = 0; r < 4; ++r) rs[r] += __shfl_xor(rs[r], off);
#pragma unroll
      for (int r = 0; r < 4; ++r)
        lrow[r] = skip ? (lrow[r] + rs[r]) : (lrow[r] * alpha[r] + rs[r]);
    }

    // ---- dropout (keepmask) + bf16 + wave-private LDS (C->A relayout) ----
#pragma unroll
    for (int r = 0; r < 4; ++r) {
      int prow = (lg * 4 + r) * PSTR + lm;
      Pw[prow +  0] = (bf16_t)(((km >> (0 + r)) & 1u)  ? S[0][r] : 0.f);
      Pw[prow + 16] = (bf16_t)(((km >> (4 + r)) & 1u)  ? S[1][r] : 0.f);
      Pw[prow + 32] = (bf16_t)(((km >> (8 + r)) & 1u)  ? S[2][r] : 0.f);
      Pw[prow + 48] = (bf16_t)(((km >> (12 + r)) & 1u) ? S[3][r] : 0.f);
    }
    asm volatile("s_waitcnt lgkmcnt(0)" ::: "memory");

    // ---- O = O*alpha (skipped when no row max grew) ----
    if (!skip) {
#pragma unroll
      for (int c = 0; c < 8; ++c)
#pragma unroll
        for (int r = 0; r < 4; ++r) Oacc[c][r] *= alpha[r];
    }

    bf16x8 aP[2];
#pragma unroll
    for (int kk = 0; kk < 2; ++kk)
      aP[kk] = *(const bf16x8*)&Pw[lm * PSTR + kk * 32 + lg * 8];

    asm volatile("s_waitcnt vmcnt(0)" ::: "memory");
    __syncthreads();                           // V tile visible to all waves

    // ---- O += P V (V frags from LDS) ----
#pragma unroll
    for (int c = 0; c < 8; ++c) {
      bf16x8 vf[2];
#pragma unroll
      for (int kk = 0; kk < 2; ++kk)
        vf[kk] = *(const bf16x8*)&KVs[(c * 16 + lm) * 64 + ((kk * 4 + lg) ^ (lm & 7)) * 8];
#pragma unroll
      for (int kk = 0; kk < 2; ++kk) Oacc[c] = mfma16(aP[kk], vf[kk], Oacc[c]);
    }
  }

  // ---- epilogue: normalize (1/l) * (1/0.9), write bf16 mid ----
  float invl[4];
#pragma unroll
  for (int r = 0; r < 4; ++r) invl[r] = (1.0f / 0.9f) / lrow[r];
#pragma unroll
  for (int c = 0; c < 8; ++c) {
    int d = c * 16 + lm;
#pragma unroll
    for (int r = 0; r < 4; ++r) {
      int bt = b * TLEN + row0 + lg * 4 + r;
      midb[(size_t)bt * DEMB + qh * 128 + d] = (bf16_t)(Oacc[c][r] * invl[r]);
    }
  }
}

// ---------------------------------------------------------------------------
extern "C" void kernel_launch(void* const* d_in, const int* in_sizes, int n_in,
                              void* d_out, int out_size, void* d_ws, size_t ws_size,
                              hipStream_t stream) {
  const float* x  = (const float*)d_in[0];
  const float* wq = (const float*)d_in[1];
  const float* wk = (const float*)d_in[2];
  const float* wv = (const float*)d_in[3];
  const float* wo = (const float*)d_in[4];
  float* out = (float*)d_out;
  float* kvc = out + ATTN_OUT_ELEMS;                    // [B,T,4,256] f32

  // workspace carve-up (~80.8 MB)
  char* ws = (char*)d_ws;
  bf16_t* Xb     = (bf16_t*)ws;                          ws += (size_t)4096 * 2048 * 2;  // 16.8MB
  bf16_t* Wqkvt  = (bf16_t*)ws;                          ws += (size_t)3072 * 2048 * 2;  // 12.6MB
  bf16_t* Wot    = (bf16_t*)ws;                          ws += (size_t)2048 * 2048 * 2;  // 8.4MB
  bf16_t* qbuf   = (bf16_t*)ws;                          ws += (size_t)2 * 16 * 2048 * 128 * 2; // 16.8MB
  bf16_t* Kbuf   = (bf16_t*)ws;                          ws += (size_t)2 * 4 * 2048 * 128 * 2;  // 4.2MB
  bf16_t* Vtb    = (bf16_t*)ws;                          ws += (size_t)2 * 4 * 128 * 2048 * 2;  // 4.2MB
  bf16_t* midb   = (bf16_t*)ws;                          ws += (size_t)4096 * 2048 * 2;  // 16.8MB
  float*  costab = (float*)ws;                           ws += (size_t)2048 * 64 * 4;    // 0.5MB
  float*  sintab = (float*)ws;                           // 0.5MB

  dim3 blk(256);
  cvt_rope<<<dim3(8704), blk, 0, stream>>>(x, Xb, costab, sintab);
  wtrans_all<<<dim3(32, 80), blk, 0, stream>>>(wq, wk, wv, wo, Wqkvt, Wot);

  gemm_bf16<1><<<dim3(32, 24), blk, 0, stream>>>(Xb, Wqkvt, nullptr, qbuf, Kbuf, kvc,
                                                 costab, sintab, 4096, 3072, 2048);
  vtrans<<<dim3(256), blk, 0, stream>>>(kvc, Vtb);
  attn_flash<<<dim3(1024), blk, 0, stream>>>(qbuf, Kbuf, Vtb, midb);
  gemm_bf16<0><<<dim3(32, 16), blk, 0, stream>>>(midb, Wot, out, nullptr, nullptr, nullptr,
                                                 nullptr, nullptr, 4096, 2048, 2048);
}

// Round 7
// 459.563 us; speedup vs baseline: 1.3160x; 1.0170x over previous
//
#include <hip/hip_runtime.h>
#include <stdint.h>

// Problem constants (fixed by reference)
#define BATCH 2
#define TLEN  2048
#define DEMB  2048
#define NHQ   16
#define NHKV  4
#define GRP   4
#define DKV   128
#define ATTN_OUT_ELEMS (BATCH*TLEN*DEMB) // 8388608
// d_out layout: [attn_output (8388608 f32) | kv_cache (B,T,4,256) f32 (4194304)]

typedef __bf16 bf16_t;
typedef __attribute__((ext_vector_type(4))) __bf16 bf16x4;
typedef __attribute__((ext_vector_type(8))) __bf16 bf16x8;
typedef __attribute__((ext_vector_type(4))) float f32x4;

__device__ __forceinline__ f32x4 mfma16(bf16x8 a, bf16x8 b, f32x4 c) {
  return __builtin_amdgcn_mfma_f32_16x16x32_bf16(a, b, c, 0, 0, 0);
}

typedef __attribute__((address_space(1))) const unsigned int as1_uint;
typedef __attribute__((address_space(3))) unsigned int as3_uint;
__device__ __forceinline__ void gload_lds16(const void* g, void* l) {
  // 16B per lane, LDS dest = l + lane*16 (wave-uniform base)
  __builtin_amdgcn_global_load_lds((as1_uint*)g, (as3_uint*)l, 16, 0, 0);
}

// ---------------------------------------------------------------------------
// threefry2x32-20, key=(0,1) (jax.random.key(1)), partitionable mode:
// per-element u64 counter (hi=0, lo=ctr), output = x0 ^ x1. Verified R1-R5.
// keep = uniform<0.9  <=>  bits < 0xE6666600 (bit-exact, verified R4/R5).
// R1-R4 session experiments: this VALU work (~124 machine-us) overlaps NOTHING
// wherever hosted (inline / standalone / GEMM-appendix all cost ~dense).
// Inline-in-attn is the cheapest home (zero extra dispatches).
// ---------------------------------------------------------------------------
__device__ __forceinline__ uint32_t rotl(uint32_t x, int r) {
  return __builtin_amdgcn_alignbit(x, x, 32 - r);
}
__device__ __forceinline__ void tf_round(uint32_t& x0, uint32_t& x1, int r) {
  x0 += x1;
  x1 = rotl(x1, r);
  x1 ^= x0;
}
__device__ __forceinline__ uint32_t threefry_bits(uint32_t ctr) {
  const uint32_t ks1 = 1u, ks2 = 0x1BD11BDBu;
  uint32_t x0 = 0u, x1 = ctr + ks1;
  tf_round(x0,x1,13); tf_round(x0,x1,15); tf_round(x0,x1,26); tf_round(x0,x1,6);
  x0 += ks1; x1 += ks2 + 1u;
  tf_round(x0,x1,17); tf_round(x0,x1,29); tf_round(x0,x1,16); tf_round(x0,x1,24);
  x0 += ks2; x1 += 0u + 2u;
  tf_round(x0,x1,13); tf_round(x0,x1,15); tf_round(x0,x1,26); tf_round(x0,x1,6);
  x0 += 0u;  x1 += ks1 + 3u;
  tf_round(x0,x1,17); tf_round(x0,x1,29); tf_round(x0,x1,16); tf_round(x0,x1,24);
  x0 += ks1; x1 += ks2 + 4u;
  tf_round(x0,x1,13); tf_round(x0,x1,15); tf_round(x0,x1,26); tf_round(x0,x1,6);
  x0 += ks2; x1 += 0u + 5u;
  return x0 ^ x1;
}

// pack one keep-bit: km = (km<<1) | (bits < 0xE6666600). 2 insts (cmp+addc)
// vs cndmask/shift/or. Bit order is producer-defined; consumer mirrors it.
__device__ __forceinline__ void pack_keep(uint32_t& km, uint32_t bits) {
  asm("v_cmp_gt_u32 vcc, 0xE6666600, %1\n\t"
      "v_addc_co_u32 %0, vcc, %0, %0, vcc"
      : "+v"(km) : "v"(bits) : "vcc");
}

// ---------------------------------------------------------------------------
// Merged preprocessing (one dispatch; all phases BW-bound so their memory
// streams overlap instead of serializing across launches):
//   bid [0,2560):      weight transpose+convert wq/wk/wv/wo -> bf16 [N][K]
//   bid [2560,10752):  X fp32 -> bf16
//   bid [10752,11264): RoPE cos/sin tables [ti=2048][d=64] (double precision)
// ---------------------------------------------------------------------------
__device__ __forceinline__ void wtrans_body(const float* __restrict__ src,
                                            bf16_t* __restrict__ dst,
                                            int N, int Kd, int k0, int n0) {
  __shared__ float t[64][65];
  const int tid = threadIdx.x;
  const int r = tid >> 4, c4 = tid & 15;
#pragma unroll
  for (int i = 0; i < 4; ++i) {
    float4 v = *(const float4*)(src + (size_t)(k0 + r + i * 16) * N + n0 + c4 * 4);
    t[r + i * 16][c4 * 4 + 0] = v.x; t[r + i * 16][c4 * 4 + 1] = v.y;
    t[r + i * 16][c4 * 4 + 2] = v.z; t[r + i * 16][c4 * 4 + 3] = v.w;
  }
  __syncthreads();
#pragma unroll
  for (int i = 0; i < 4; ++i) {
    int idx = tid + i * 256;
    int rn = idx >> 4, ck = idx & 15;
    bf16x4 o = {(bf16_t)t[ck * 4 + 0][rn], (bf16_t)t[ck * 4 + 1][rn],
                (bf16_t)t[ck * 4 + 2][rn], (bf16_t)t[ck * 4 + 3][rn]};
    *(bf16x4*)(dst + (size_t)(n0 + rn) * Kd + k0 + ck * 4) = o;
  }
}

__global__ __launch_bounds__(256) void prep_all(const float* __restrict__ x,
                                                const float* __restrict__ wq,
                                                const float* __restrict__ wk,
                                                const float* __restrict__ wv,
                                                const float* __restrict__ wo,
                                                bf16_t* __restrict__ Xb,
                                                bf16_t* __restrict__ dqkv,
                                                bf16_t* __restrict__ dwo,
                                                float* __restrict__ ct,
                                                float* __restrict__ st) {
  const int bid = blockIdx.x;
  if (bid < 2560) {                            // weight transpose
    const int by = bid >> 5, k0 = (bid & 31) * 64;
    if (by < 32)      wtrans_body(wq, dqkv,                        2048, 2048, k0, by * 64);
    else if (by < 40) wtrans_body(wk, dqkv + (size_t)2048 * 2048,  512,  2048, k0, (by - 32) * 64);
    else if (by < 48) wtrans_body(wv, dqkv + (size_t)2560 * 2048,  512,  2048, k0, (by - 40) * 64);
    else              wtrans_body(wo, dwo,                         2048, 2048, k0, (by - 48) * 64);
  } else if (bid < 10752) {                    // X cvt (8192 blocks, exact)
    int i = (bid - 2560) * 256 + threadIdx.x;
    float4 v = *(const float4*)(x + (size_t)i * 4);
    bf16x4 o = {(bf16_t)v.x, (bf16_t)v.y, (bf16_t)v.z, (bf16_t)v.w};
    *(bf16x4*)(Xb + (size_t)i * 4) = o;
  } else {                                     // RoPE tables
    int i = (bid - 10752) * 256 + threadIdx.x; // 131072 total
    int ti = i >> 6, d = i & 63;
    double theta = exp((double)(-2 * d) * (9.210340371976184 / 128.0)); // ln(1e4)/128
    float tick = (float)ti * (float)theta;
    ct[i] = (float)cos((double)tick);
    st[i] = (float)sin((double)tick);
  }
}

// ---------------------------------------------------------------------------
// bf16 MFMA GEMM: C[M,N] = Ab[M,K] (row-major) @ Wt[N,K]^T
// 128x128 tile, BK=64, 4 waves, 64x64/wave; col-tile pairing keeps RoPE
// partners (d, d+64) in-wave for MODE 1. global_load_lds(16B) staging with
// XOR chunk swizzle. MODE 0: f32 C. MODE 1: QKV epilogue (RoPE via tables).
// ---------------------------------------------------------------------------
template<int MODE>
__global__ __launch_bounds__(256) void gemm_bf16(
    const bf16_t* __restrict__ Ab, const bf16_t* __restrict__ Wt,
    float* __restrict__ Cout, bf16_t* __restrict__ qbuf,
    bf16_t* __restrict__ Kbuf, float* __restrict__ kvout,
    const float* __restrict__ costab, const float* __restrict__ sintab,
    int M, int N, int K) {
  __shared__ bf16_t As[128 * 64];
  __shared__ bf16_t Bs[128 * 64];
  const int tid = threadIdx.x;
  const int w = tid >> 6, lane = tid & 63;
  const int lm = lane & 15, lg = lane >> 4;
  const int wy = w & 1, wx = w >> 1;
  const int mblk = blockIdx.x * 128, nblk = blockIdx.y * 128;

  const int srow = lane >> 3;                 // row within 8-row group
  const int schunk = (lane & 7) ^ srow;       // fetch swizzled chunk
  const bf16_t* Ag = Ab + (size_t)(mblk + w * 32 + srow) * K + schunk * 8;
  const bf16_t* Bg = Wt + (size_t)(nblk + w * 32 + srow) * K + schunk * 8;
  bf16_t* AsW = As + (w * 32) * 64;
  bf16_t* BsW = Bs + (w * 32) * 64;

  f32x4 acc[4][4];
#pragma unroll
  for (int i = 0; i < 4; ++i)
#pragma unroll
    for (int j = 0; j < 4; ++j) acc[i][j] = (f32x4)0.0f;

  const int tcol0 = wx * 2;

  for (int k0 = 0; k0 < K; k0 += 64) {
    __syncthreads();
#pragma unroll
    for (int inst = 0; inst < 4; ++inst) {
      gload_lds16(Ag + (size_t)(inst * 8) * K + k0, AsW + inst * 8 * 64);
      gload_lds16(Bg + (size_t)(inst * 8) * K + k0, BsW + inst * 8 * 64);
    }
    asm volatile("s_waitcnt vmcnt(0)" ::: "memory");
    __syncthreads();
#pragma unroll
    for (int ks = 0; ks < 2; ++ks) {
      const int chunk = ((ks * 4 + lg) ^ (lane & 7)) * 8;
      bf16x8 af[4], bfr[4];
#pragma unroll
      for (int i = 0; i < 4; ++i) {
        int mrow = wy * 64 + i * 16 + lm;
        af[i] = *(const bf16x8*)&As[mrow * 64 + chunk];
      }
#pragma unroll
      for (int j = 0; j < 4; ++j) {
        int tc = tcol0 + (j & 1) + (j >> 1) * 4;
        int nrow = tc * 16 + lm;
        bfr[j] = *(const bf16x8*)&Bs[nrow * 64 + chunk];
      }
#pragma unroll
      for (int i = 0; i < 4; ++i)
#pragma unroll
        for (int j = 0; j < 4; ++j) acc[i][j] = mfma16(af[i], bfr[j], acc[i][j]);
    }
  }

  if (MODE == 0) {
#pragma unroll
    for (int i = 0; i < 4; ++i)
#pragma unroll
      for (int j = 0; j < 4; ++j) {
        int tc = tcol0 + (j & 1) + (j >> 1) * 4;
        int col = nblk + tc * 16 + lm;
#pragma unroll
        for (int r = 0; r < 4; ++r) {
          int row = mblk + wy * 64 + i * 16 + lg * 4 + r;
          Cout[(size_t)row * N + col] = acc[i][j][r];
        }
      }
  } else {
    // QKV epilogue with fused RoPE via tables. d in [0,64), partner d+64.
    const float qscale = 0.08838834764831843f;   // 1/sqrt(128)
#pragma unroll
    for (int i = 0; i < 4; ++i) {
#pragma unroll
      for (int r = 0; r < 4; ++r) {
        int row = mblk + wy * 64 + i * 16 + lg * 4 + r;   // bt
        int ti = row & (TLEN - 1), b = row >> 11;
#pragma unroll
        for (int jp = 0; jp < 2; ++jp) {
          float lo = acc[i][jp][r], hi = acc[i][jp + 2][r];
          int d = wx * 32 + jp * 16 + lm;                 // [0,64)
          int nl = nblk + d;                              // low-half global col
          if (nblk < 2048) {                              // q
            int qh = nl >> 7;
            float cs = costab[ti * 64 + d], sn = sintab[ti * 64 + d];
            float o0 = (lo * cs - hi * sn) * qscale;
            float o1 = (hi * cs + lo * sn) * qscale;
            size_t qo = (((size_t)(b * 16 + qh)) * TLEN + ti) * 128 + d;
            qbuf[qo] = (bf16_t)o0; qbuf[qo + 64] = (bf16_t)o1;
          } else if (nblk < 2560) {                       // k
            int hh = (nl - 2048) >> 7;
            float cs = costab[ti * 64 + d], sn = sintab[ti * 64 + d];
            float o0 = lo * cs - hi * sn;
            float o1 = hi * cs + lo * sn;
            size_t ko = (((size_t)(b * 4 + hh)) * TLEN + ti) * 128 + d;
            Kbuf[ko] = (bf16_t)o0; Kbuf[ko + 64] = (bf16_t)o1;
            size_t kvo = (size_t)row * 1024 + hh * 256 + d;
            kvout[kvo] = o0; kvout[kvo + 64] = o1;
          } else {                                        // v
            int hh = (nl - 2560) >> 7;
            size_t kvo = (size_t)row * 1024 + hh * 256 + 128 + d;
            kvout[kvo] = lo; kvout[kvo + 64] = hi;
          }
        }
      }
    }
  }
}

// ---------------------------------------------------------------------------
// V transpose: kv f32 [b][ti][h][128v @ +128] -> Vtb bf16 [b][h][d=128][tj=2048]
// ---------------------------------------------------------------------------
__global__ __launch_bounds__(256) void vtrans(const float* __restrict__ kvout,
                                              bf16_t* __restrict__ Vtb) {
  __shared__ bf16_t t[128][72];
  const int bx = blockIdx.x;          // (b*4+h)*32 + tt
  const int tt = bx & 31, bh = bx >> 5;
  const int b = bh >> 2, h = bh & 3;
  const int ti0 = tt * 64;
  const float* src = kvout + ((size_t)b * TLEN + ti0) * 1024 + h * 256 + 128;
  for (int idx = threadIdx.x; idx < 64 * 32; idx += 256) {
    int ti = idx >> 5, c4 = idx & 31;
    float4 v = *(const float4*)(src + (size_t)ti * 1024 + c4 * 4);
    t[c4 * 4 + 0][ti] = (bf16_t)v.x; t[c4 * 4 + 1][ti] = (bf16_t)v.y;
    t[c4 * 4 + 2][ti] = (bf16_t)v.z; t[c4 * 4 + 3][ti] = (bf16_t)v.w;
  }
  __syncthreads();
  bf16_t* dst = Vtb + (size_t)bh * 128 * TLEN + ti0;
  for (int idx = threadIdx.x; idx < 128 * 16; idx += 256) {
    int d = idx >> 4, ck = idx & 15;
    bf16x4 o = {t[d][ck * 4 + 0], t[d][ck * 4 + 1], t[d][ck * 4 + 2], t[d][ck * 4 + 3]};
    *(bf16x4*)(dst + (size_t)d * TLEN + ck * 4) = o;
  }
}

// ---------------------------------------------------------------------------
// Flash attention, bf16 MFMA. K and V time-share one 16KB LDS buffer
// (R6-verified structure; R0 and R6 measured identical — LDS/barriers are
// not the limiter; the kernel sits at a VALU-issue equilibrium dominated by
// the irreducible inline threefry). This round: s_setprio around both MFMA
// clusters (T5: +4-7% measured on multi-block attn) and 2-inst cmp+addc
// keep-bit packing (bit order MSB-first (r,ct); consumer mirrors).
// ---------------------------------------------------------------------------
#define PSTR 68
__global__ __launch_bounds__(256, 3) void attn_flash(
    const bf16_t* __restrict__ qb, const bf16_t* __restrict__ Kb,
    const bf16_t* __restrict__ Vtb, bf16_t* __restrict__ midb) {
  __shared__ bf16_t KVs[64 * 128];   // K: [tj][d] / V: [d][tj], time-shared
  __shared__ bf16_t P_lds[64 * PSTR];
  const int tid = threadIdx.x;
  const int w = tid >> 6, lane = tid & 63;
  const int lm = lane & 15, lg = lane >> 4;

  const int bx = blockIdx.x;
  const int bhalf = bx >> 9, idx = bx & 511;
  const int bqh = idx & 31, t4 = idx >> 5;          // t4 in 0..15
  const int qt = bhalf ? (31 - t4) : t4;            // 0..31
  const int qh = bqh & 15, b = bqh >> 4;
  const int h = qh & 3, g = qh >> 2;

  const bf16_t* qbase = qb + (((size_t)(b * 16 + qh)) * TLEN + qt * 64 + w * 16) * 128;
  const bf16_t* kbase = Kb + ((size_t)(b * 4 + h)) * TLEN * 128;
  const bf16_t* vbase = Vtb + ((size_t)(b * 4 + h)) * 128 * TLEN;

  // staging geometry (wave w stages K rows w*16..+15, V rows w*32..+31)
  const int krow_l = lane >> 4;              // 0..3 (4 rows per instr)
  const int kchunk = lane & 15;              // 16 chunks of 16B per 256B row
  const int vrow_l = lane >> 3;              // 0..7 (8 rows per instr)
  const int vchunk = (lane & 7) ^ (vrow_l & 7);
  const bf16_t* ksrc[4]; const bf16_t* vsrc[4];
  bf16_t* kdst[4]; bf16_t* vdst[4];
#pragma unroll
  for (int j = 0; j < 4; ++j) {
    int klr = w * 16 + j * 4 + krow_l;       // tile-local K row
    ksrc[j] = kbase + (size_t)klr * 128 + (size_t)((kchunk ^ (j * 4 + krow_l)) * 8);
    kdst[j] = KVs + (w * 16 + j * 4) * 128;
    int vd = w * 32 + j * 8 + vrow_l;        // V row (d)
    vsrc[j] = vbase + (size_t)vd * TLEN + (size_t)(vchunk * 8);
    vdst[j] = KVs + (w * 32 + j * 8) * 64;
  }

  // Q A-frags (16 rows); q already scaled by 1/sqrt(128)
  bf16x8 qf[4];
#pragma unroll
  for (int kk = 0; kk < 4; ++kk)
    qf[kk] = *(const bf16x8*)(qbase + (size_t)lm * 128 + kk * 32 + lg * 8);

  float mrow[4], lrow[4];
  f32x4 Oacc[8];
#pragma unroll
  for (int r = 0; r < 4; ++r) { mrow[r] = -3.0e38f; lrow[r] = 0.f; }
#pragma unroll
  for (int c = 0; c < 8; ++c) Oacc[c] = (f32x4)0.0f;

  const int row0 = qt * 64 + w * 16;           // wave's first q row
  const int nkt = qt + 1;                      // K-tiles (uniform across waves)
  const float L2E = 1.4426950408889634f;
  const uint32_t hdr = (uint32_t)((b * 4 + g) * 4 + h);
  bf16_t* Pw = P_lds + (w * 16) * PSTR;

  for (int kt = 0; kt < nkt; ++kt) {
    const int tj0 = kt * 64;
    __syncthreads();                           // prev iter's PV reads done
    // ---- async stage K tile (4 DMA instrs per wave) ----
#pragma unroll
    for (int j = 0; j < 4; ++j) gload_lds16(ksrc[j] + (size_t)tj0 * 128, kdst[j]);

    // ---- threefry keepmask (fills the K-DMA window); bit (r,ct) lands at
    //      position 15-(r*4+ct) via MSB-first (km<<1)|keep packing ----
    uint32_t km = 0;
#pragma unroll
    for (int r = 0; r < 4; ++r) {
      uint32_t cb = (hdr << 22) + ((uint32_t)(row0 + lg * 4 + r) << 11)
                  + (uint32_t)(tj0 + lm);
#pragma unroll
      for (int ct = 0; ct < 4; ++ct)
        pack_keep(km, threefry_bits(cb + (uint32_t)(ct * 16)));
    }
    asm volatile("s_waitcnt vmcnt(0)" ::: "memory");
    __syncthreads();                           // K tile visible to all waves

    // ---- S = Q K^T (K frags from LDS) ----
    f32x4 S[4];
    __builtin_amdgcn_s_setprio(1);
#pragma unroll
    for (int ct = 0; ct < 4; ++ct) {
      S[ct] = (f32x4)0.0f;
      bf16x8 kf[4];
#pragma unroll
      for (int kk = 0; kk < 4; ++kk)
        kf[kk] = *(const bf16x8*)&KVs[(ct * 16 + lm) * 128 + ((kk * 4 + lg) ^ lm) * 8];
#pragma unroll
      for (int kk = 0; kk < 4; ++kk) S[ct] = mfma16(qf[kk], kf[kk], S[ct]);
    }
    __builtin_amdgcn_s_setprio(0);

    __syncthreads();                           // all waves done reading K
    // ---- async stage V tile into the SAME buffer ----
#pragma unroll
    for (int j = 0; j < 4; ++j) gload_lds16(vsrc[j] + tj0, vdst[j]);

    // ---- causal mask (diagonal tile only) ----
    if (tj0 + 63 > row0) {
#pragma unroll
      for (int ct = 0; ct < 4; ++ct) {
        int tj = tj0 + ct * 16 + lm;
#pragma unroll
        for (int r = 0; r < 4; ++r) {
          int ti = row0 + lg * 4 + r;
          if (tj > ti) S[ct][r] = -1.0e30f;
        }
      }
    }

    // ---- online softmax (exact alpha-skip; fills the V-DMA window) ----
    float alpha[4];
    bool skip;
    {
      float pm[4];
#pragma unroll
      for (int r = 0; r < 4; ++r)
        pm[r] = fmaxf(fmaxf(S[0][r], S[1][r]), fmaxf(S[2][r], S[3][r]));
#pragma unroll
      for (int off = 1; off < 16; off <<= 1)
#pragma unroll
        for (int r = 0; r < 4; ++r) pm[r] = fmaxf(pm[r], __shfl_xor(pm[r], off));
      bool nu = (pm[0] <= mrow[0]) & (pm[1] <= mrow[1]) &
                (pm[2] <= mrow[2]) & (pm[3] <= mrow[3]);
      skip = __all(nu);
      if (!skip) {
#pragma unroll
        for (int r = 0; r < 4; ++r) {
          float mn = fmaxf(mrow[r], pm[r]);
          alpha[r] = exp2f((mrow[r] - mn) * L2E);
          mrow[r] = mn;
        }
      }
      float rs[4] = {0.f, 0.f, 0.f, 0.f};
#pragma unroll
      for (int ct = 0; ct < 4; ++ct)
#pragma unroll
        for (int r = 0; r < 4; ++r) {
          float p = exp2f((S[ct][r] - mrow[r]) * L2E);
          S[ct][r] = p;
          rs[r] += p;
        }
#pragma unroll
      for (int off = 1; off < 16; off <<= 1)
#pragma unroll
        for (int r = 0; r < 4; ++r) rs[r] += __shfl_xor(rs[r], off);
#pragma unroll
      for (int r = 0; r < 4; ++r)
        lrow[r] = skip ? (lrow[r] + rs[r]) : (lrow[r] * alpha[r] + rs[r]);
    }

    // ---- dropout (keepmask, MSB-first layout) + bf16 + P relayout ----
#pragma unroll
    for (int r = 0; r < 4; ++r) {
      int prow = (lg * 4 + r) * PSTR + lm;
      Pw[prow +  0] = (bf16_t)(((km >> (15 - 4 * r)) & 1u) ? S[0][r] : 0.f);
      Pw[prow + 16] = (bf16_t)(((km >> (14 - 4 * r)) & 1u) ? S[1][r] : 0.f);
      Pw[prow + 32] = (bf16_t)(((km >> (13 - 4 * r)) & 1u) ? S[2][r] : 0.f);
      Pw[prow + 48] = (bf16_t)(((km >> (12 - 4 * r)) & 1u) ? S[3][r] : 0.f);
    }
    asm volatile("s_waitcnt lgkmcnt(0)" ::: "memory");

    // ---- O = O*alpha (skipped when no row max grew) ----
    if (!skip) {
#pragma unroll
      for (int c = 0; c < 8; ++c)
#pragma unroll
        for (int r = 0; r < 4; ++r) Oacc[c][r] *= alpha[r];
    }

    bf16x8 aP[2];
#pragma unroll
    for (int kk = 0; kk < 2; ++kk)
      aP[kk] = *(const bf16x8*)&Pw[lm * PSTR + kk * 32 + lg * 8];

    asm volatile("s_waitcnt vmcnt(0)" ::: "memory");
    __syncthreads();                           // V tile visible to all waves

    // ---- O += P V (V frags from LDS) ----
    __builtin_amdgcn_s_setprio(1);
#pragma unroll
    for (int c = 0; c < 8; ++c) {
      bf16x8 vf[2];
#pragma unroll
      for (int kk = 0; kk < 2; ++kk)
        vf[kk] = *(const bf16x8*)&KVs[(c * 16 + lm) * 64 + ((kk * 4 + lg) ^ (lm & 7)) * 8];
#pragma unroll
      for (int kk = 0; kk < 2; ++kk) Oacc[c] = mfma16(aP[kk], vf[kk], Oacc[c]);
    }
    __builtin_amdgcn_s_setprio(0);
  }

  // ---- epilogue: normalize (1/l) * (1/0.9), write bf16 mid ----
  float invl[4];
#pragma unroll
  for (int r = 0; r < 4; ++r) invl[r] = (1.0f / 0.9f) / lrow[r];
#pragma unroll
  for (int c = 0; c < 8; ++c) {
    int d = c * 16 + lm;
#pragma unroll
    for (int r = 0; r < 4; ++r) {
      int bt = b * TLEN + row0 + lg * 4 + r;
      midb[(size_t)bt * DEMB + qh * 128 + d] = (bf16_t)(Oacc[c][r] * invl[r]);
    }
  }
}

// ---------------------------------------------------------------------------
extern "C" void kernel_launch(void* const* d_in, const int* in_sizes, int n_in,
                              void* d_out, int out_size, void* d_ws, size_t ws_size,
                              hipStream_t stream) {
  const float* x  = (const float*)d_in[0];
  const float* wq = (const float*)d_in[1];
  const float* wk = (const float*)d_in[2];
  const float* wv = (const float*)d_in[3];
  const float* wo = (const float*)d_in[4];
  float* out = (float*)d_out;
  float* kvc = out + ATTN_OUT_ELEMS;                    // [B,T,4,256] f32

  // workspace carve-up (~80.8 MB)
  char* ws = (char*)d_ws;
  bf16_t* Xb     = (bf16_t*)ws;                          ws += (size_t)4096 * 2048 * 2;  // 16.8MB
  bf16_t* Wqkvt  = (bf16_t*)ws;                          ws += (size_t)3072 * 2048 * 2;  // 12.6MB
  bf16_t* Wot    = (bf16_t*)ws;                          ws += (size_t)2048 * 2048 * 2;  // 8.4MB
  bf16_t* qbuf   = (bf16_t*)ws;                          ws += (size_t)2 * 16 * 2048 * 128 * 2; // 16.8MB
  bf16_t* Kbuf   = (bf16_t*)ws;                          ws += (size_t)2 * 4 * 2048 * 128 * 2;  // 4.2MB
  bf16_t* Vtb    = (bf16_t*)ws;                          ws += (size_t)2 * 4 * 128 * 2048 * 2;  // 4.2MB
  bf16_t* midb   = (bf16_t*)ws;                          ws += (size_t)4096 * 2048 * 2;  // 16.8MB
  float*  costab = (float*)ws;                           ws += (size_t)2048 * 64 * 4;    // 0.5MB
  float*  sintab = (float*)ws;                           // 0.5MB

  dim3 blk(256);
  prep_all<<<dim3(11264), blk, 0, stream>>>(x, wq, wk, wv, wo, Xb, Wqkvt, Wot,
                                            costab, sintab);
  gemm_bf16<1><<<dim3(32, 24), blk, 0, stream>>>(Xb, Wqkvt, nullptr, qbuf, Kbuf, kvc,
                                                 costab, sintab, 4096, 3072, 2048);
  vtrans<<<dim3(256), blk, 0, stream>>>(kvc, Vtb);
  attn_flash<<<dim3(1024), blk, 0, stream>>>(qbuf, Kbuf, Vtb, midb);
  gemm_bf16<0><<<dim3(32, 16), blk, 0, stream>>>(midb, Wot, out, nullptr, nullptr, nullptr,
                                                 nullptr, nullptr, 4096, 2048, 2048);
}